// Round 1
// baseline (731.070 us; speedup 1.0000x reference)
//
#include <hip/hip_runtime.h>

#define G_    1024
#define NSV   16
#define NTRK  64
#define HID   128
#define KNN   8
#define TPB   512

__device__ __forceinline__ float elu_f(float x) {
    return x > 0.f ? x : expm1f(x);
}

// One block per graph. 512 threads: c = tid&127 (channel lane), g4 = tid>>7 (row group).
// LDS plan (~88 KB, 1 block/CU on gfx950's 160KB LDS):
//   sA [64*128]  : trk embeddings  -> later bsrc2
//   sB [128*65]  : h_trk -> h_sv -> conv1 scores[64][17] -> f1T[128][65]
//   sC [4160]    : sv_emb[16][132] @0  + bsrc1[16][128] @2112  -> conv2 scores[64][65]
__global__ __launch_bounds__(TPB)
void fused_net(const float* __restrict__ x_sv,  const float* __restrict__ x_trk,
               const float* __restrict__ W_sv1, const float* __restrict__ b_sv1,
               const float* __restrict__ W_sv2, const float* __restrict__ b_sv2,
               const float* __restrict__ W_trk1,const float* __restrict__ b_trk1,
               const float* __restrict__ W_trk2,const float* __restrict__ b_trk2,
               const float* __restrict__ W_c1,  const float* __restrict__ b_c1,
               const float* __restrict__ W_c2,  const float* __restrict__ b_c2,
               const float* __restrict__ W_o1,  const float* __restrict__ b_o1,
               const float* __restrict__ W_o2,  const float* __restrict__ b_o2,
               const float* __restrict__ W_o3,  const float* __restrict__ b_o3,
               const float* __restrict__ W_o4,  const float* __restrict__ b_o4,
               float* __restrict__ out)
{
    __shared__ float sA[NTRK * HID];      // 32 KB
    __shared__ float sB[HID * 65];        // 32.5 KB
    __shared__ float sC[4160];            // 16.25 KB
    __shared__ int   sIdx[NTRK * KNN];    // 2 KB
    __shared__ float sX[NTRK * 8 + NSV * 2];
    __shared__ float sNrm[NTRK];
    __shared__ float sPP[4 * HID];
    __shared__ float sHd[100];

    const int g   = blockIdx.x;
    const int tid = threadIdx.x;
    const int c   = tid & (HID - 1);
    const int g4  = tid >> 7;             // 0..3

    // ---- P0: stage raw inputs ----
    if (tid < NTRK * 8) sX[tid] = x_trk[(size_t)g * NTRK * 8 + tid];
    if (tid < NSV * 2)  sX[NTRK * 8 + tid] = x_sv[(size_t)g * NSV * 2 + tid];
    __syncthreads();

    // ---- P1: trk MLP layer 1 -> h in sB[64][128] ----
    {
        float w[8];
        #pragma unroll
        for (int i = 0; i < 8; i++) w[i] = W_trk1[i * HID + c];
        const float b1 = b_trk1[c];
        #pragma unroll
        for (int i = 0; i < 16; i++) {
            const int r = g4 * 16 + i;
            float acc = b1;
            #pragma unroll
            for (int k = 0; k < 8; k++) acc = fmaf(sX[r * 8 + k], w[k], acc);
            sB[r * HID + c] = elu_f(acc);
        }
    }
    __syncthreads();

    // ---- P2: trk MLP layer 2 -> trk in sA[64][128] ----
    {
        float acc[16];
        const float b2 = b_trk2[c];
        #pragma unroll
        for (int i = 0; i < 16; i++) acc[i] = b2;
        for (int k0 = 0; k0 < HID; k0 += 4) {
            const float w0 = W_trk2[(k0 + 0) * HID + c];
            const float w1 = W_trk2[(k0 + 1) * HID + c];
            const float w2 = W_trk2[(k0 + 2) * HID + c];
            const float w3 = W_trk2[(k0 + 3) * HID + c];
            #pragma unroll
            for (int i = 0; i < 16; i++) {
                const int r = g4 * 16 + i;
                const float4 h4 = *(const float4*)&sB[r * HID + k0];
                acc[i] = fmaf(h4.x, w0, acc[i]);
                acc[i] = fmaf(h4.y, w1, acc[i]);
                acc[i] = fmaf(h4.z, w2, acc[i]);
                acc[i] = fmaf(h4.w, w3, acc[i]);
            }
        }
        #pragma unroll
        for (int i = 0; i < 16; i++) {
            const int r = g4 * 16 + i;
            sA[r * HID + c] = fmaxf(acc[i], 0.f);
        }
    }
    __syncthreads();

    // ---- P3: sv MLP layer 1 -> h_sv in sB[16][128] ----
    {
        const float* xsv = &sX[NTRK * 8];
        const float w0 = W_sv1[c], w1 = W_sv1[HID + c];
        const float b1 = b_sv1[c];
        #pragma unroll
        for (int i = 0; i < 4; i++) {
            const int s = g4 * 4 + i;
            const float acc = fmaf(xsv[s * 2 + 1], w1, fmaf(xsv[s * 2], w0, b1));
            sB[s * HID + c] = elu_f(acc);
        }
    }
    __syncthreads();
    // ---- P3b: sv MLP layer 2 -> sv_emb in sC[16][132] ----
    {
        float acc[4];
        const float b2 = b_sv2[c];
        #pragma unroll
        for (int i = 0; i < 4; i++) acc[i] = b2;
        for (int k0 = 0; k0 < HID; k0 += 4) {
            const float w0 = W_sv2[(k0 + 0) * HID + c];
            const float w1 = W_sv2[(k0 + 1) * HID + c];
            const float w2 = W_sv2[(k0 + 2) * HID + c];
            const float w3 = W_sv2[(k0 + 3) * HID + c];
            #pragma unroll
            for (int i = 0; i < 4; i++) {
                const int s = g4 * 4 + i;
                const float4 h4 = *(const float4*)&sB[s * HID + k0];
                acc[i] = fmaf(h4.x, w0, acc[i]);
                acc[i] = fmaf(h4.y, w1, acc[i]);
                acc[i] = fmaf(h4.z, w2, acc[i]);
                acc[i] = fmaf(h4.w, w3, acc[i]);
            }
        }
        #pragma unroll
        for (int i = 0; i < 4; i++) {
            const int s = g4 * 4 + i;
            sC[s * 132 + c] = fmaxf(acc[i], 0.f);
        }
    }
    __syncthreads();

    // ---- P4: conv1 scores: score[q][s] = |sv_s|^2 - 2 trk_q . sv_s  (|trk_q|^2 is row-const) ----
    if (tid < NSV) {
        float s2 = 0.f;
        for (int d = 0; d < HID; d += 4) {
            const float4 v = *(const float4*)&sC[tid * 132 + d];
            s2 += v.x * v.x + v.y * v.y + v.z * v.z + v.w * v.w;
        }
        sNrm[tid] = s2;
    }
    __syncthreads();
    {
        const int q  = tid >> 3;
        const int s0 = tid & 7;
        float acc0 = 0.f, acc1 = 0.f;
        for (int d = 0; d < HID; d += 4) {
            const float4 tq = *(const float4*)&sA[q * HID + d];
            const float4 v0 = *(const float4*)&sC[s0 * 132 + d];
            const float4 v1 = *(const float4*)&sC[(s0 + 8) * 132 + d];
            acc0 += tq.x * v0.x + tq.y * v0.y + tq.z * v0.z + tq.w * v0.w;
            acc1 += tq.x * v1.x + tq.y * v1.y + tq.z * v1.z + tq.w * v1.w;
        }
        sB[q * 17 + s0]     = sNrm[s0]     - 2.f * acc0;
        sB[q * 17 + s0 + 8] = sNrm[s0 + 8] - 2.f * acc1;
    }
    __syncthreads();

    // ---- P5: conv1 top-8 of 16 (strict <, lowest index on tie == lax.top_k) ----
    if (tid < NTRK) {
        float dr[NSV];
        #pragma unroll
        for (int s = 0; s < NSV; s++) dr[s] = sB[tid * 17 + s];
        #pragma unroll
        for (int j = 0; j < KNN; j++) {
            float best = 3.4e38f; int bi = 0;
            #pragma unroll
            for (int s = 0; s < NSV; s++)
                if (dr[s] < best) { best = dr[s]; bi = s; }
            sIdx[tid * KNN + j] = bi;
            dr[bi] = 3.4e38f;
        }
    }
    __syncthreads();

    // ---- P6: bsrc1[s][c] = sv_s @ Wc1_bot -> sC[2112 + s*128 + c] ----
    {
        float acc[4] = {0.f, 0.f, 0.f, 0.f};
        for (int d = 0; d < HID; d++) {
            const float w = W_c1[(HID + d) * HID + c];
            #pragma unroll
            for (int i = 0; i < 4; i++) {
                const int s = g4 * 4 + i;
                acc[i] = fmaf(sC[s * 132 + d], w, acc[i]);
            }
        }
        #pragma unroll
        for (int i = 0; i < 4; i++) {
            const int s = g4 * 4 + i;
            sC[2112 + s * HID + c] = acc[i];
        }
    }
    __syncthreads();

    // ---- P7: a1[q] = trk_q @ (Wc1_top - Wc1_bot) + b_c1 ; f1T[c][q] = max_j elu(a1+bsrc1) ----
    {
        float a1[16];
        const float bb = b_c1[c];
        #pragma unroll
        for (int i = 0; i < 16; i++) a1[i] = bb;
        for (int d0 = 0; d0 < HID; d0 += 4) {
            float wd[4];
            #pragma unroll
            for (int j = 0; j < 4; j++) {
                const int d = d0 + j;
                wd[j] = W_c1[d * HID + c] - W_c1[(HID + d) * HID + c];
            }
            #pragma unroll
            for (int i = 0; i < 16; i++) {
                const int q = g4 * 16 + i;
                const float4 t4 = *(const float4*)&sA[q * HID + d0];
                a1[i] = fmaf(t4.x, wd[0], a1[i]);
                a1[i] = fmaf(t4.y, wd[1], a1[i]);
                a1[i] = fmaf(t4.z, wd[2], a1[i]);
                a1[i] = fmaf(t4.w, wd[3], a1[i]);
            }
        }
        #pragma unroll
        for (int i = 0; i < 16; i++) {
            const int q = g4 * 16 + i;
            float m = -3.4e38f;
            #pragma unroll
            for (int j = 0; j < KNN; j++) {
                const int s = sIdx[q * KNN + j];
                m = fmaxf(m, elu_f(a1[i] + sC[2112 + s * HID + c]));
            }
            sB[c * 65 + q] = m;   // f1 transposed
        }
    }
    __syncthreads();

    // ---- P8a: a2[q] = trk_q @ (Wc2_top - Wc2_bot) + b_c2 (registers) ----
    float a2[16];
    {
        const float bb = b_c2[c];
        #pragma unroll
        for (int i = 0; i < 16; i++) a2[i] = bb;
        for (int d0 = 0; d0 < HID; d0 += 4) {
            float wd[4];
            #pragma unroll
            for (int j = 0; j < 4; j++) {
                const int d = d0 + j;
                wd[j] = W_c2[d * HID + c] - W_c2[(HID + d) * HID + c];
            }
            #pragma unroll
            for (int i = 0; i < 16; i++) {
                const int q = g4 * 16 + i;
                const float4 t4 = *(const float4*)&sA[q * HID + d0];
                a2[i] = fmaf(t4.x, wd[0], a2[i]);
                a2[i] = fmaf(t4.y, wd[1], a2[i]);
                a2[i] = fmaf(t4.z, wd[2], a2[i]);
                a2[i] = fmaf(t4.w, wd[3], a2[i]);
            }
        }
    }

    // ---- P8b: conv2 scores: score[q][s] = |f1_s|^2 - 2 trk_q . f1_s -> sC[64][65] ----
    if (tid < NTRK) {
        float s2 = 0.f;
        for (int d = 0; d < HID; d++) {
            const float v = sB[d * 65 + tid];
            s2 = fmaf(v, v, s2);
        }
        sNrm[tid] = s2;
    }
    __syncthreads();
    {
        const int s  = tid & 63;
        const int qg = tid >> 6;     // 0..7
        float acc[8];
        #pragma unroll
        for (int i = 0; i < 8; i++) acc[i] = 0.f;
        for (int d = 0; d < HID; d++) {
            const float f = sB[d * 65 + s];
            #pragma unroll
            for (int i = 0; i < 8; i++) {
                const int q = qg * 8 + i;
                acc[i] = fmaf(sA[q * HID + d], f, acc[i]);
            }
        }
        const float ns = sNrm[s];
        #pragma unroll
        for (int i = 0; i < 8; i++) {
            const int q = qg * 8 + i;
            sC[q * 65 + s] = ns - 2.f * acc[i];
        }
    }
    __syncthreads();

    // ---- P8c: conv2 top-8 of 64 ----
    if (tid < NTRK) {
        #pragma unroll
        for (int j = 0; j < KNN; j++) {
            float best = 3.4e38f; int bi = 0;
            for (int s = 0; s < NTRK; s++) {
                const float v = sC[tid * 65 + s];
                if (v < best) { best = v; bi = s; }
            }
            sIdx[tid * KNN + j] = bi;
            sC[tid * 65 + bi] = 3.4e38f;
        }
    }
    __syncthreads();

    // ---- P8d: bsrc2[s][c] = f1_s @ Wc2_bot -> sA (trk is dead now) ----
    {
        float acc[16];
        #pragma unroll
        for (int i = 0; i < 16; i++) acc[i] = 0.f;
        for (int d = 0; d < HID; d++) {
            const float w = W_c2[(HID + d) * HID + c];
            #pragma unroll
            for (int i = 0; i < 16; i++) {
                const int s = g4 * 16 + i;
                acc[i] = fmaf(sB[d * 65 + s], w, acc[i]);
            }
        }
        #pragma unroll
        for (int i = 0; i < 16; i++) {
            const int s = g4 * 16 + i;
            sA[s * HID + c] = acc[i];
        }
    }
    __syncthreads();

    // ---- P8e: f2 messages + partial mean-pool ----
    {
        float psum = 0.f;
        #pragma unroll
        for (int i = 0; i < 16; i++) {
            const int q = g4 * 16 + i;
            float m = -3.4e38f;
            #pragma unroll
            for (int j = 0; j < KNN; j++) {
                const int s = sIdx[q * KNN + j];
                m = fmaxf(m, elu_f(a2[i] + sA[s * HID + c]));
            }
            psum += m;
        }
        sPP[g4 * HID + c] = psum;
    }
    __syncthreads();

    // ---- P9: head ----
    if (tid < HID) {
        const float p = (sPP[tid] + sPP[HID + tid] + sPP[2 * HID + tid] + sPP[3 * HID + tid]) * (1.f / 64.f);
        sPP[tid] = p;
    }
    __syncthreads();
    if (tid < 64) {
        float acc = b_o1[tid];
        for (int d = 0; d < HID; d++) acc = fmaf(sPP[d], W_o1[d * 64 + tid], acc);
        sHd[tid] = elu_f(acc);
    }
    __syncthreads();
    if (tid < 32) {
        float acc = b_o2[tid];
        for (int d = 0; d < 64; d++) acc = fmaf(sHd[d], W_o2[d * 32 + tid], acc);
        sHd[64 + tid] = elu_f(acc);
    }
    __syncthreads();
    if (tid < 4) {
        float acc = b_o3[tid];
        for (int d = 0; d < 32; d++) acc = fmaf(sHd[64 + d], W_o3[d * 4 + tid], acc);
        sHd[96 + tid] = elu_f(acc);
    }
    __syncthreads();
    if (tid == 0) {
        float acc = b_o4[0];
        #pragma unroll
        for (int d = 0; d < 4; d++) acc = fmaf(sHd[96 + d], W_o4[d], acc);
        out[g] = acc;            // output 0: (G,1)
        out[G_ + g] = (float)g;  // output 1: batch = arange(G)
    }
}

extern "C" void kernel_launch(void* const* d_in, const int* in_sizes, int n_in,
                              void* d_out, int out_size, void* d_ws, size_t ws_size,
                              hipStream_t stream) {
    const float* x_sv   = (const float*)d_in[0];
    const float* x_trk  = (const float*)d_in[1];
    const float* W_sv1  = (const float*)d_in[2];
    const float* b_sv1  = (const float*)d_in[3];
    const float* W_sv2  = (const float*)d_in[4];
    const float* b_sv2  = (const float*)d_in[5];
    const float* W_trk1 = (const float*)d_in[6];
    const float* b_trk1 = (const float*)d_in[7];
    const float* W_trk2 = (const float*)d_in[8];
    const float* b_trk2 = (const float*)d_in[9];
    const float* W_c1   = (const float*)d_in[10];
    const float* b_c1   = (const float*)d_in[11];
    const float* W_c2   = (const float*)d_in[12];
    const float* b_c2   = (const float*)d_in[13];
    const float* W_o1   = (const float*)d_in[14];
    const float* b_o1   = (const float*)d_in[15];
    const float* W_o2   = (const float*)d_in[16];
    const float* b_o2   = (const float*)d_in[17];
    const float* W_o3   = (const float*)d_in[18];
    const float* b_o3   = (const float*)d_in[19];
    const float* W_o4   = (const float*)d_in[20];
    const float* b_o4   = (const float*)d_in[21];
    float* out = (float*)d_out;

    fused_net<<<G_, TPB, 0, stream>>>(x_sv, x_trk, W_sv1, b_sv1, W_sv2, b_sv2,
                                      W_trk1, b_trk1, W_trk2, b_trk2,
                                      W_c1, b_c1, W_c2, b_c2,
                                      W_o1, b_o1, W_o2, b_o2, W_o3, b_o3, W_o4, b_o4,
                                      out);
}

// Round 2
// 574.970 us; speedup vs baseline: 1.2715x; 1.2715x over previous
//
#include <hip/hip_runtime.h>

#define G_    1024
#define TPB   512

__device__ __forceinline__ float elu_f(float x) {
    return x > 0.f ? x : expm1f(x);
}

// Swizzled LDS layouts (all conflict-free or 2-way):
//  sA (8192f): trk[64][128] then bsrc2[64][128], rotated rows
#define ROT_A(r, d)  ((r)*128 + (((d) + 4*(r)) & 127))
//  sC rows 0..15: sv_emb[16][128], rotated
#define ROT_SV(s, d) ((s)*128 + (((d) + 4*(s)) & 127))
//  sC floats 2048..4095: bsrc1[16][128], rotated
#define BS1(s, c)    (2048 + (s)*128 + (((c) + 4*(s)) & 127))
//  sB (8192f): h_trk[64][128] -> scores1[64][17] -> f1^T (c-major, XOR swizzle)
#define F1T(c, q)    ((c)*64 + ((q) ^ ((c) & 63)))
//  sC (4096f): conv2 scores [64][64], XOR swizzle
#define SC2(q, s)    ((q)*64 + ((s) ^ (q)))

__global__ void prep_wdiff(const float* __restrict__ Wc1,
                           const float* __restrict__ Wc2,
                           float* __restrict__ wd) {
    const int i = blockIdx.x * 256 + threadIdx.x;   // 0..16383
    if (i < 16384) {
        wd[i]         = Wc1[i] - Wc1[16384 + i];
        wd[16384 + i] = Wc2[i] - Wc2[16384 + i];
    }
}

template<bool USE_WD>
__global__ __launch_bounds__(TPB, 4)
void fused_net(const float* __restrict__ x_sv,  const float* __restrict__ x_trk,
               const float* __restrict__ W_sv1, const float* __restrict__ b_sv1,
               const float* __restrict__ W_sv2, const float* __restrict__ b_sv2,
               const float* __restrict__ W_trk1,const float* __restrict__ b_trk1,
               const float* __restrict__ W_trk2,const float* __restrict__ b_trk2,
               const float* __restrict__ W_c1,  const float* __restrict__ b_c1,
               const float* __restrict__ W_c2,  const float* __restrict__ b_c2,
               const float* __restrict__ W_o1,  const float* __restrict__ b_o1,
               const float* __restrict__ W_o2,  const float* __restrict__ b_o2,
               const float* __restrict__ W_o3,  const float* __restrict__ b_o3,
               const float* __restrict__ W_o4,  const float* __restrict__ b_o4,
               const float* __restrict__ wd,
               float* __restrict__ out)
{
    __shared__ float sA[8192];   // 32 KB
    __shared__ float sB[8192];   // 32 KB
    __shared__ float sC[4096];   // 16 KB   (total exactly 80 KB -> 2 blocks/CU)

    const int g    = blockIdx.x;
    const int tid  = threadIdx.x;
    const int c128 = tid & 127;
    const int g4   = tid >> 7;          // 0..3
    const int cb   = tid & 31;          // col base for 4-col tiling
    const int rg   = tid >> 5;          // row-group 0..15
    unsigned int* sCu = (unsigned int*)sC;

    // ---- P0: stage raw inputs: x_trk at sC[2048..2560), x_sv at sC[2560..2592) ----
    sC[2048 + tid] = x_trk[(size_t)g * 512 + tid];
    if (tid < 32) sC[2560 + tid] = x_sv[(size_t)g * 32 + tid];
    __syncthreads();

    // ---- P1: trk MLP layer 1 -> h_trk in sB[r][c] ----
    {
        float w[8];
        #pragma unroll
        for (int k = 0; k < 8; k++) w[k] = W_trk1[k * 128 + c128];
        const float b1 = b_trk1[c128];
        #pragma unroll
        for (int i = 0; i < 16; i++) {
            const int r = g4 * 16 + i;
            float acc = b1;
            #pragma unroll
            for (int k = 0; k < 8; k++) acc = fmaf(sC[2048 + r * 8 + k], w[k], acc);
            sB[r * 128 + c128] = elu_f(acc);
        }
    }
    __syncthreads();

    // ---- P2: trk MLP layer 2 -> trk in sA (rotated). 4 cols x 4 rows per thread ----
    {
        const int r0 = rg * 4;
        float acc[4][4];
        #pragma unroll
        for (int i = 0; i < 4; i++)
            #pragma unroll
            for (int k = 0; k < 4; k++) acc[i][k] = b_trk2[cb + 32 * k];
        for (int d0 = 0; d0 < 128; d0 += 4) {
            float wv[4][4];
            #pragma unroll
            for (int dj = 0; dj < 4; dj++)
                #pragma unroll
                for (int k = 0; k < 4; k++)
                    wv[dj][k] = W_trk2[(d0 + dj) * 128 + cb + 32 * k];
            #pragma unroll
            for (int i = 0; i < 4; i++) {
                const float4 h = *(const float4*)&sB[(r0 + i) * 128 + d0];
                #pragma unroll
                for (int k = 0; k < 4; k++) {
                    acc[i][k] = fmaf(h.x, wv[0][k], acc[i][k]);
                    acc[i][k] = fmaf(h.y, wv[1][k], acc[i][k]);
                    acc[i][k] = fmaf(h.z, wv[2][k], acc[i][k]);
                    acc[i][k] = fmaf(h.w, wv[3][k], acc[i][k]);
                }
            }
        }
        #pragma unroll
        for (int i = 0; i < 4; i++)
            #pragma unroll
            for (int k = 0; k < 4; k++)
                sA[ROT_A(r0 + i, cb + 32 * k)] = fmaxf(acc[i][k], 0.f);
    }
    __syncthreads();

    // ---- P3: sv MLP layer 1 -> h_sv in sB rows 0..15 ----
    {
        const float w0 = W_sv1[c128], w1 = W_sv1[128 + c128];
        const float b1 = b_sv1[c128];
        #pragma unroll
        for (int i = 0; i < 4; i++) {
            const int s = g4 * 4 + i;
            sB[s * 128 + c128] =
                elu_f(fmaf(sC[2560 + s * 2 + 1], w1, fmaf(sC[2560 + s * 2], w0, b1)));
        }
    }
    __syncthreads();

    // ---- P3b: sv MLP layer 2 -> sv_emb in sC rows 0..15 (rotated). 4 cols x 1 row ----
    {
        const int s = rg;    // 0..15
        float acc[4];
        #pragma unroll
        for (int k = 0; k < 4; k++) acc[k] = b_sv2[cb + 32 * k];
        for (int d0 = 0; d0 < 128; d0 += 4) {
            const float4 h = *(const float4*)&sB[s * 128 + d0];
            #pragma unroll
            for (int dj = 0; dj < 4; dj++) {
                const float hv = (dj == 0) ? h.x : (dj == 1) ? h.y : (dj == 2) ? h.z : h.w;
                #pragma unroll
                for (int k = 0; k < 4; k++)
                    acc[k] = fmaf(hv, W_sv2[(d0 + dj) * 128 + cb + 32 * k], acc[k]);
            }
        }
        #pragma unroll
        for (int k = 0; k < 4; k++) sC[ROT_SV(s, cb + 32 * k)] = fmaxf(acc[k], 0.f);
    }
    __syncthreads();

    // ---- P4: conv1 scores -> sB[q*17+s] ; norms inlined ----
    {
        const int q  = tid >> 3;
        const int s0 = tid & 7;
        float d0a = 0.f, d1a = 0.f, n0 = 0.f, n1 = 0.f;
        for (int d = 0; d < 128; d += 4) {
            const float4 t  = *(const float4*)&sA[ROT_A(q, d)];
            const float4 v0 = *(const float4*)&sC[ROT_SV(s0, d)];
            const float4 v1 = *(const float4*)&sC[ROT_SV(s0 + 8, d)];
            d0a += t.x * v0.x + t.y * v0.y + t.z * v0.z + t.w * v0.w;
            d1a += t.x * v1.x + t.y * v1.y + t.z * v1.z + t.w * v1.w;
            n0  += v0.x * v0.x + v0.y * v0.y + v0.z * v0.z + v0.w * v0.w;
            n1  += v1.x * v1.x + v1.y * v1.y + v1.z * v1.z + v1.w * v1.w;
        }
        sB[q * 17 + s0]     = n0 - 2.f * d0a;
        sB[q * 17 + s0 + 8] = n1 - 2.f * d1a;
    }
    __syncthreads();

    // ---- P6: bsrc1[s][c] = sv_s @ Wc1_bot -> sC (rotated). 4 cols x 1 row ----
    {
        const int s = rg;
        float acc[4] = {0.f, 0.f, 0.f, 0.f};
        for (int d0 = 0; d0 < 128; d0 += 4) {
            const float4 e = *(const float4*)&sC[ROT_SV(s, d0)];
            #pragma unroll
            for (int dj = 0; dj < 4; dj++) {
                const float ev = (dj == 0) ? e.x : (dj == 1) ? e.y : (dj == 2) ? e.z : e.w;
                #pragma unroll
                for (int k = 0; k < 4; k++)
                    acc[k] = fmaf(ev, W_c1[(128 + d0 + dj) * 128 + cb + 32 * k], acc[k]);
            }
        }
        #pragma unroll
        for (int k = 0; k < 4; k++) sC[BS1(s, cb + 32 * k)] = acc[k];
    }
    __syncthreads();

    // ---- P5: conv1 top-8 of 16, packed nibbles -> sCu[q] (sv_emb row 0 is dead) ----
    if (tid < 64) {
        float dr[16];
        #pragma unroll
        for (int s = 0; s < 16; s++) dr[s] = sB[tid * 17 + s];
        unsigned int pack = 0u;
        #pragma unroll
        for (int j = 0; j < 8; j++) {
            float best = 3.4e38f; int bi = 0;
            #pragma unroll
            for (int s = 0; s < 16; s++)
                if (dr[s] < best) { best = dr[s]; bi = s; }
            pack |= (unsigned int)bi << (4 * j);
            dr[bi] = 3.4e38f;
        }
        sCu[tid] = pack;
    }
    __syncthreads();

    // ---- P7: a1 = trk @ Wdiff1 + b ; f1^T = max_j elu(a1 + bsrc1[idx]) -> sB ----
    {
        const int q0 = rg * 4;
        float a[4][4];
        #pragma unroll
        for (int i = 0; i < 4; i++)
            #pragma unroll
            for (int k = 0; k < 4; k++) a[i][k] = b_c1[cb + 32 * k];
        for (int d0 = 0; d0 < 128; d0 += 4) {
            float wv[4][4];
            #pragma unroll
            for (int dj = 0; dj < 4; dj++)
                #pragma unroll
                for (int k = 0; k < 4; k++) {
                    const int d = d0 + dj, cc = cb + 32 * k;
                    wv[dj][k] = USE_WD ? wd[d * 128 + cc]
                                       : (W_c1[d * 128 + cc] - W_c1[(128 + d) * 128 + cc]);
                }
            #pragma unroll
            for (int i = 0; i < 4; i++) {
                const float4 t = *(const float4*)&sA[ROT_A(q0 + i, d0)];
                #pragma unroll
                for (int k = 0; k < 4; k++) {
                    a[i][k] = fmaf(t.x, wv[0][k], a[i][k]);
                    a[i][k] = fmaf(t.y, wv[1][k], a[i][k]);
                    a[i][k] = fmaf(t.z, wv[2][k], a[i][k]);
                    a[i][k] = fmaf(t.w, wv[3][k], a[i][k]);
                }
            }
        }
        #pragma unroll
        for (int i = 0; i < 4; i++) {
            const int q = q0 + i;
            const unsigned int pack = sCu[q];
            float m[4] = {-3.4e38f, -3.4e38f, -3.4e38f, -3.4e38f};
            #pragma unroll
            for (int j = 0; j < 8; j++) {
                const int s = (pack >> (4 * j)) & 15;
                #pragma unroll
                for (int k = 0; k < 4; k++)
                    m[k] = fmaxf(m[k], elu_f(a[i][k] + sC[BS1(s, cb + 32 * k)]));
            }
            #pragma unroll
            for (int k = 0; k < 4; k++) sB[F1T(cb + 32 * k, q)] = m[k];
        }
    }
    __syncthreads();

    // ---- P8a: a2 = trk @ Wdiff2 + b  (kept in registers, same thread mapping) ----
    float a2r[4][4];
    {
        const int q0 = rg * 4;
        #pragma unroll
        for (int i = 0; i < 4; i++)
            #pragma unroll
            for (int k = 0; k < 4; k++) a2r[i][k] = b_c2[cb + 32 * k];
        for (int d0 = 0; d0 < 128; d0 += 4) {
            float wv[4][4];
            #pragma unroll
            for (int dj = 0; dj < 4; dj++)
                #pragma unroll
                for (int k = 0; k < 4; k++) {
                    const int d = d0 + dj, cc = cb + 32 * k;
                    wv[dj][k] = USE_WD ? wd[16384 + d * 128 + cc]
                                       : (W_c2[d * 128 + cc] - W_c2[(128 + d) * 128 + cc]);
                }
            #pragma unroll
            for (int i = 0; i < 4; i++) {
                const float4 t = *(const float4*)&sA[ROT_A(q0 + i, d0)];
                #pragma unroll
                for (int k = 0; k < 4; k++) {
                    a2r[i][k] = fmaf(t.x, wv[0][k], a2r[i][k]);
                    a2r[i][k] = fmaf(t.y, wv[1][k], a2r[i][k]);
                    a2r[i][k] = fmaf(t.z, wv[2][k], a2r[i][k]);
                    a2r[i][k] = fmaf(t.w, wv[3][k], a2r[i][k]);
                }
            }
        }
    }

    // ---- P8b: conv2 scores -> sC (SC2 swizzle); norms inlined ----
    {
        const int s  = tid & 63;
        const int qg = tid >> 6;
        float acc[8];
        #pragma unroll
        for (int i = 0; i < 8; i++) acc[i] = 0.f;
        float nrm = 0.f;
        for (int d0 = 0; d0 < 128; d0 += 4) {
            const float f0 = sB[F1T(d0 + 0, s)];
            const float f1 = sB[F1T(d0 + 1, s)];
            const float f2 = sB[F1T(d0 + 2, s)];
            const float f3 = sB[F1T(d0 + 3, s)];
            nrm += f0 * f0 + f1 * f1 + f2 * f2 + f3 * f3;
            #pragma unroll
            for (int i = 0; i < 8; i++) {
                const float4 t = *(const float4*)&sA[ROT_A(qg * 8 + i, d0)];
                acc[i] += t.x * f0 + t.y * f1 + t.z * f2 + t.w * f3;
            }
        }
        #pragma unroll
        for (int i = 0; i < 8; i++)
            sC[SC2(qg * 8 + i, s)] = nrm - 2.f * acc[i];
    }
    __syncthreads();

    // ---- P8c: conv2 top-8 of 64, packed bytes -> sCu[2q],sCu[2q+1] ----
    if (tid < 64) {
        const int q = tid;
        unsigned int lo = 0u, hi = 0u;
        #pragma unroll
        for (int j = 0; j < 8; j++) {
            float best = 3.4e38f; int bi = 0;
            for (int s = 0; s < 64; s++) {
                const float v = sC[SC2(q, s)];
                if (v < best) { best = v; bi = s; }
            }
            sC[SC2(q, bi)] = 3.4e38f;
            if (j < 4) lo |= (unsigned int)bi << (8 * j);
            else       hi |= (unsigned int)bi << (8 * (j - 4));
        }
        sCu[2 * q]     = lo;
        sCu[2 * q + 1] = hi;
    }
    __syncthreads();

    // ---- P8d: bsrc2[s][c] = f1_s @ Wc2_bot -> sA (rotated; trk dead) ----
    {
        const int r0 = rg * 4;
        float acc[4][4];
        #pragma unroll
        for (int i = 0; i < 4; i++)
            #pragma unroll
            for (int k = 0; k < 4; k++) acc[i][k] = 0.f;
        for (int d = 0; d < 128; d++) {
            float wv[4];
            #pragma unroll
            for (int k = 0; k < 4; k++) wv[k] = W_c2[(128 + d) * 128 + cb + 32 * k];
            #pragma unroll
            for (int i = 0; i < 4; i++) {
                const float f = sB[F1T(d, r0 + i)];
                #pragma unroll
                for (int k = 0; k < 4; k++) acc[i][k] = fmaf(f, wv[k], acc[i][k]);
            }
        }
        #pragma unroll
        for (int i = 0; i < 4; i++)
            #pragma unroll
            for (int k = 0; k < 4; k++)
                sA[ROT_A(r0 + i, cb + 32 * k)] = acc[i][k];
    }
    __syncthreads();

    // ---- P8e: f2 messages + partial mean-pool -> sC[128 + rg*128 + c] ----
    {
        const int q0 = rg * 4;
        float ps[4] = {0.f, 0.f, 0.f, 0.f};
        #pragma unroll
        for (int i = 0; i < 4; i++) {
            const int q = q0 + i;
            const unsigned int lo = sCu[2 * q];
            const unsigned int hi = sCu[2 * q + 1];
            float m[4] = {-3.4e38f, -3.4e38f, -3.4e38f, -3.4e38f};
            #pragma unroll
            for (int j = 0; j < 8; j++) {
                const int s = (int)(((j < 4) ? (lo >> (8 * j)) : (hi >> (8 * (j - 4)))) & 63u);
                #pragma unroll
                for (int k = 0; k < 4; k++)
                    m[k] = fmaxf(m[k], elu_f(a2r[i][k] + sA[ROT_A(s, cb + 32 * k)]));
            }
            #pragma unroll
            for (int k = 0; k < 4; k++) ps[k] += m[k];
        }
        #pragma unroll
        for (int k = 0; k < 4; k++) sC[128 + rg * 128 + cb + 32 * k] = ps[k];
    }
    __syncthreads();

    // ---- P9: pooled mean + head (scratch overlaid in dead sC) ----
    if (tid < 128) {
        float p = 0.f;
        #pragma unroll
        for (int t = 0; t < 16; t++) p += sC[128 + t * 128 + tid];
        sC[2176 + tid] = p * (1.f / 64.f);
    }
    __syncthreads();
    if (tid < 64) {
        float acc = b_o1[tid];
        for (int d = 0; d < 128; d++) acc = fmaf(sC[2176 + d], W_o1[d * 64 + tid], acc);
        sC[2304 + tid] = elu_f(acc);
    }
    __syncthreads();
    if (tid < 32) {
        float acc = b_o2[tid];
        for (int d = 0; d < 64; d++) acc = fmaf(sC[2304 + d], W_o2[d * 32 + tid], acc);
        sC[2368 + tid] = elu_f(acc);
    }
    __syncthreads();
    if (tid < 4) {
        float acc = b_o3[tid];
        for (int d = 0; d < 32; d++) acc = fmaf(sC[2368 + d], W_o3[d * 4 + tid], acc);
        sC[2400 + tid] = elu_f(acc);
    }
    __syncthreads();
    if (tid == 0) {
        float acc = b_o4[0];
        #pragma unroll
        for (int d = 0; d < 4; d++) acc = fmaf(sC[2400 + d], W_o4[d], acc);
        out[g] = acc;            // output 0: (G,1)
        out[G_ + g] = (float)g;  // output 1: batch = arange(G)
    }
}

extern "C" void kernel_launch(void* const* d_in, const int* in_sizes, int n_in,
                              void* d_out, int out_size, void* d_ws, size_t ws_size,
                              hipStream_t stream) {
    const float* x_sv   = (const float*)d_in[0];
    const float* x_trk  = (const float*)d_in[1];
    const float* W_sv1  = (const float*)d_in[2];
    const float* b_sv1  = (const float*)d_in[3];
    const float* W_sv2  = (const float*)d_in[4];
    const float* b_sv2  = (const float*)d_in[5];
    const float* W_trk1 = (const float*)d_in[6];
    const float* b_trk1 = (const float*)d_in[7];
    const float* W_trk2 = (const float*)d_in[8];
    const float* b_trk2 = (const float*)d_in[9];
    const float* W_c1   = (const float*)d_in[10];
    const float* b_c1   = (const float*)d_in[11];
    const float* W_c2   = (const float*)d_in[12];
    const float* b_c2   = (const float*)d_in[13];
    const float* W_o1   = (const float*)d_in[14];
    const float* b_o1   = (const float*)d_in[15];
    const float* W_o2   = (const float*)d_in[16];
    const float* b_o2   = (const float*)d_in[17];
    const float* W_o3   = (const float*)d_in[18];
    const float* b_o3   = (const float*)d_in[19];
    const float* W_o4   = (const float*)d_in[20];
    const float* b_o4   = (const float*)d_in[21];
    float* out = (float*)d_out;

    const bool use_wd = (ws_size >= 2u * 16384u * sizeof(float)) && d_ws != nullptr;
    float* wdp = (float*)d_ws;

    if (use_wd) {
        prep_wdiff<<<64, 256, 0, stream>>>(W_c1, W_c2, wdp);
        fused_net<true><<<G_, TPB, 0, stream>>>(x_sv, x_trk, W_sv1, b_sv1, W_sv2, b_sv2,
                                                W_trk1, b_trk1, W_trk2, b_trk2,
                                                W_c1, b_c1, W_c2, b_c2,
                                                W_o1, b_o1, W_o2, b_o2, W_o3, b_o3,
                                                W_o4, b_o4, wdp, out);
    } else {
        fused_net<false><<<G_, TPB, 0, stream>>>(x_sv, x_trk, W_sv1, b_sv1, W_sv2, b_sv2,
                                                 W_trk1, b_trk1, W_trk2, b_trk2,
                                                 W_c1, b_c1, W_c2, b_c2,
                                                 W_o1, b_o1, W_o2, b_o2, W_o3, b_o3,
                                                 W_o4, b_o4, (const float*)nullptr, out);
    }
}

// Round 4
// 335.679 us; speedup vs baseline: 2.1779x; 1.7129x over previous
//
#include <hip/hip_runtime.h>

#define G_    1024
#define TPB   512
#define INF_F 3.4e38f

__device__ __forceinline__ float elu_f(float x) { return x > 0.f ? x : expm1f(x); }

// Rotated row layouts (rotation is a multiple of 4 -> float4 access stays aligned)
#define ROT(r, d)    ((r)*128 + (((d) + 4*(r)) & 127))
#define BS1(s, c)    (2048 + (s)*128 + (((c) + 4*(s)) & 127))

// NOTE: macro params must not be named x/y/z/w (field-name capture!)
#define FMA4(acc_, sc_, wv_) do { (acc_).x = fmaf((sc_),(wv_).x,(acc_).x); \
                                  (acc_).y = fmaf((sc_),(wv_).y,(acc_).y); \
                                  (acc_).z = fmaf((sc_),(wv_).z,(acc_).z); \
                                  (acc_).w = fmaf((sc_),(wv_).w,(acc_).w); } while(0)
#define MAX4(mm_, bb_)       do { (mm_).x = fmaxf((mm_).x,(bb_).x); \
                                  (mm_).y = fmaxf((mm_).y,(bb_).y); \
                                  (mm_).z = fmaxf((mm_).z,(bb_).z); \
                                  (mm_).w = fmaxf((mm_).w,(bb_).w); } while(0)

__global__ void prep_wdiff(const float* __restrict__ Wc1,
                           const float* __restrict__ Wc2,
                           float* __restrict__ wd) {
    const int i = blockIdx.x * 256 + threadIdx.x;   // 0..16383
    if (i < 16384) {
        wd[i]         = Wc1[i] - Wc1[16384 + i];
        wd[16384 + i] = Wc2[i] - Wc2[16384 + i];
    }
}

template<bool USE_WD>
__global__ __launch_bounds__(TPB, 4)
void fused_net(const float* __restrict__ x_sv,  const float* __restrict__ x_trk,
               const float* __restrict__ W_sv1, const float* __restrict__ b_sv1,
               const float* __restrict__ W_sv2, const float* __restrict__ b_sv2,
               const float* __restrict__ W_trk1,const float* __restrict__ b_trk1,
               const float* __restrict__ W_trk2,const float* __restrict__ b_trk2,
               const float* __restrict__ W_c1,  const float* __restrict__ b_c1,
               const float* __restrict__ W_c2,  const float* __restrict__ b_c2,
               const float* __restrict__ W_o1,  const float* __restrict__ b_o1,
               const float* __restrict__ W_o2,  const float* __restrict__ b_o2,
               const float* __restrict__ W_o3,  const float* __restrict__ b_o3,
               const float* __restrict__ W_o4,  const float* __restrict__ b_o4,
               const float* __restrict__ wd,
               float* __restrict__ out)
{
    __shared__ float sA[8192];   // 32 KB : trk (rot) -> bsrc2 (rot)
    __shared__ float sB[8192];   // 32 KB : h_trk -> h_sv(rows0..15) -> f1 (rot) -> partials+head
    __shared__ float sC[4096];   // 16 KB : x stage -> sv_emb(rot)+bsrc1 -> conv2 scores
    // total exactly 80 KB -> 2 blocks/CU

    const int g    = blockIdx.x;
    const int tid  = threadIdx.x;
    const int c128 = tid & 127;
    const int g4   = tid >> 7;          // 0..3
    const int cq   = tid & 31;
    const int c0   = cq * 4;            // 4 contiguous cols per thread
    const int rg   = tid >> 5;          // 0..15
    const int lane_hi = tid & 32;       // upper/lower half-wave base for shfl

    // ---- P0: stage raw inputs: x_trk at sC[2048..2560), x_sv at sC[2560..2592) ----
    sC[2048 + tid] = x_trk[(size_t)g * 512 + tid];
    if (tid < 32) sC[2560 + tid] = x_sv[(size_t)g * 32 + tid];
    __syncthreads();

    // ---- P1: trk MLP layer 1 -> h_trk in sB[r][c] ----
    {
        float w[8];
        #pragma unroll
        for (int k = 0; k < 8; k++) w[k] = W_trk1[k * 128 + c128];
        const float b1 = b_trk1[c128];
        #pragma unroll
        for (int i = 0; i < 16; i++) {
            const int r = g4 * 16 + i;
            float acc = b1;
            #pragma unroll
            for (int k = 0; k < 8; k++) acc = fmaf(sC[2048 + r * 8 + k], w[k], acc);
            sB[r * 128 + c128] = elu_f(acc);
        }
    }
    __syncthreads();

    // ---- P2: trk MLP layer 2 -> trk in sA (rot). 4 rows x 4 contiguous cols ----
    {
        const int r0 = rg * 4;
        float4 acc[4];
        const float4 bz = *(const float4*)&b_trk2[c0];
        #pragma unroll
        for (int i = 0; i < 4; i++) acc[i] = bz;
        for (int d0 = 0; d0 < 128; d0 += 4) {
            const float4 w0 = *(const float4*)&W_trk2[(d0 + 0) * 128 + c0];
            const float4 w1 = *(const float4*)&W_trk2[(d0 + 1) * 128 + c0];
            const float4 w2 = *(const float4*)&W_trk2[(d0 + 2) * 128 + c0];
            const float4 w3 = *(const float4*)&W_trk2[(d0 + 3) * 128 + c0];
            #pragma unroll
            for (int i = 0; i < 4; i++) {
                const float4 h = *(const float4*)&sB[(r0 + i) * 128 + d0];
                FMA4(acc[i], h.x, w0); FMA4(acc[i], h.y, w1);
                FMA4(acc[i], h.z, w2); FMA4(acc[i], h.w, w3);
            }
        }
        #pragma unroll
        for (int i = 0; i < 4; i++) {
            float4 r;
            r.x = fmaxf(acc[i].x, 0.f); r.y = fmaxf(acc[i].y, 0.f);
            r.z = fmaxf(acc[i].z, 0.f); r.w = fmaxf(acc[i].w, 0.f);
            *(float4*)&sA[ROT(r0 + i, c0)] = r;
        }
    }
    __syncthreads();

    // ---- P3: sv MLP layer 1 -> h_sv in sB rows 0..15 ----
    {
        const float w0 = W_sv1[c128], w1 = W_sv1[128 + c128];
        const float b1 = b_sv1[c128];
        #pragma unroll
        for (int i = 0; i < 4; i++) {
            const int s = g4 * 4 + i;
            sB[s * 128 + c128] =
                elu_f(fmaf(sC[2560 + s * 2 + 1], w1, fmaf(sC[2560 + s * 2], w0, b1)));
        }
    }
    __syncthreads();

    // ---- P3b: sv MLP layer 2 -> sv_emb in sC rows 0..15 (rot) ----
    {
        const int s = rg;
        float4 acc = *(const float4*)&b_sv2[c0];
        for (int d0 = 0; d0 < 128; d0 += 4) {
            const float4 w0 = *(const float4*)&W_sv2[(d0 + 0) * 128 + c0];
            const float4 w1 = *(const float4*)&W_sv2[(d0 + 1) * 128 + c0];
            const float4 w2 = *(const float4*)&W_sv2[(d0 + 2) * 128 + c0];
            const float4 w3 = *(const float4*)&W_sv2[(d0 + 3) * 128 + c0];
            const float4 h = *(const float4*)&sB[s * 128 + d0];
            FMA4(acc, h.x, w0); FMA4(acc, h.y, w1);
            FMA4(acc, h.z, w2); FMA4(acc, h.w, w3);
        }
        float4 r;
        r.x = fmaxf(acc.x, 0.f); r.y = fmaxf(acc.y, 0.f);
        r.z = fmaxf(acc.z, 0.f); r.w = fmaxf(acc.w, 0.f);
        *(float4*)&sC[ROT(s, c0)] = r;
    }
    __syncthreads();

    // ---- Phase5: P6 (bsrc1) + P4 (conv1 scores, regs) + P5 (top-8 of 16, shfl) ----
    unsigned int pack1;
    {
        // P6: bsrc1[s=rg][c0..c0+3] = sv_s @ Wc1_bot  (writes sC[2048..4096) only)
        {
            const int s = rg;
            float4 acc = {0.f, 0.f, 0.f, 0.f};
            for (int d0 = 0; d0 < 128; d0 += 4) {
                const float4 e  = *(const float4*)&sC[ROT(s, d0)];
                const float4 w0 = *(const float4*)&W_c1[(128 + d0 + 0) * 128 + c0];
                const float4 w1 = *(const float4*)&W_c1[(128 + d0 + 1) * 128 + c0];
                const float4 w2 = *(const float4*)&W_c1[(128 + d0 + 2) * 128 + c0];
                const float4 w3 = *(const float4*)&W_c1[(128 + d0 + 3) * 128 + c0];
                FMA4(acc, e.x, w0); FMA4(acc, e.y, w1);
                FMA4(acc, e.z, w2); FMA4(acc, e.w, w3);
            }
            *(float4*)&sC[BS1(s, c0)] = acc;
        }
        // P4: scores (q = tid>>3, lane j = tid&7 holds s = j and j+8), registers only
        const int q  = tid >> 3;
        const int s0 = tid & 7;
        float d0a = 0.f, d1a = 0.f, n0 = 0.f, n1 = 0.f;
        for (int d0 = 0; d0 < 128; d0 += 4) {
            const float4 t  = *(const float4*)&sA[ROT(q, d0)];
            const float4 v0 = *(const float4*)&sC[ROT(s0, d0)];
            const float4 v1 = *(const float4*)&sC[ROT(s0 + 8, d0)];
            d0a += t.x * v0.x + t.y * v0.y + t.z * v0.z + t.w * v0.w;
            d1a += t.x * v1.x + t.y * v1.y + t.z * v1.z + t.w * v1.w;
            n0  += v0.x * v0.x + v0.y * v0.y + v0.z * v0.z + v0.w * v0.w;
            n1  += v1.x * v1.x + v1.y * v1.y + v1.z * v1.z + v1.w * v1.w;
        }
        float sc0 = fmaf(-2.f, d0a, n0);
        float sc1 = fmaf(-2.f, d1a, n1);
        // P5: 8 extraction rounds, butterfly min over the 8-lane group (tie -> lower s)
        pack1 = 0u;
        #pragma unroll
        for (int r = 0; r < 8; r++) {
            float bv = sc0; int bs = s0;
            if (sc1 < bv) { bv = sc1; bs = s0 + 8; }
            #pragma unroll
            for (int o = 1; o <= 4; o <<= 1) {
                const float ov = __shfl_xor(bv, o, 8);
                const int   os = __shfl_xor(bs, o, 8);
                if (ov < bv || (ov == bv && os < bs)) { bv = ov; bs = os; }
            }
            pack1 |= (unsigned int)bs << (4 * r);
            if (bs == s0)     sc0 = INF_F;
            if (bs == s0 + 8) sc1 = INF_F;
        }
    }
    __syncthreads();

    // ---- Phase6: fused a1/a2 GEMMs + f1 epilogue (elu after max) ----
    float4 a2v[4];
    {
        const int q0 = rg * 4;
        float4 a1[4];
        const float4 bc1 = *(const float4*)&b_c1[c0];
        const float4 bc2 = *(const float4*)&b_c2[c0];
        #pragma unroll
        for (int i = 0; i < 4; i++) { a1[i] = bc1; a2v[i] = bc2; }
        for (int d0 = 0; d0 < 128; d0 += 4) {
            float4 t[4];
            #pragma unroll
            for (int i = 0; i < 4; i++) t[i] = *(const float4*)&sA[ROT(q0 + i, d0)];
            #pragma unroll
            for (int dj = 0; dj < 4; dj++) {
                float4 wv;
                if (USE_WD) wv = *(const float4*)&wd[(d0 + dj) * 128 + c0];
                else {
                    const float4 wa = *(const float4*)&W_c1[(d0 + dj) * 128 + c0];
                    const float4 wb = *(const float4*)&W_c1[(128 + d0 + dj) * 128 + c0];
                    wv.x = wa.x - wb.x; wv.y = wa.y - wb.y;
                    wv.z = wa.z - wb.z; wv.w = wa.w - wb.w;
                }
                FMA4(a1[0], ((const float*)&t[0])[dj], wv);
                FMA4(a1[1], ((const float*)&t[1])[dj], wv);
                FMA4(a1[2], ((const float*)&t[2])[dj], wv);
                FMA4(a1[3], ((const float*)&t[3])[dj], wv);
            }
            #pragma unroll
            for (int dj = 0; dj < 4; dj++) {
                float4 wv;
                if (USE_WD) wv = *(const float4*)&wd[16384 + (d0 + dj) * 128 + c0];
                else {
                    const float4 wa = *(const float4*)&W_c2[(d0 + dj) * 128 + c0];
                    const float4 wb = *(const float4*)&W_c2[(128 + d0 + dj) * 128 + c0];
                    wv.x = wa.x - wb.x; wv.y = wa.y - wb.y;
                    wv.z = wa.z - wb.z; wv.w = wa.w - wb.w;
                }
                FMA4(a2v[0], ((const float*)&t[0])[dj], wv);
                FMA4(a2v[1], ((const float*)&t[1])[dj], wv);
                FMA4(a2v[2], ((const float*)&t[2])[dj], wv);
                FMA4(a2v[3], ((const float*)&t[3])[dj], wv);
            }
        }
        // epilogue: f1[q] = elu(a1 + max_j bsrc1[idx_j])  (elu monotone -> elu after max)
        #pragma unroll
        for (int i = 0; i < 4; i++) {
            const int q = q0 + i;
            const unsigned int pk = __shfl(pack1, 8 * i + lane_hi);
            float4 m = {-INF_F, -INF_F, -INF_F, -INF_F};
            #pragma unroll
            for (int j = 0; j < 8; j++) {
                const int s = (int)((pk >> (4 * j)) & 15u);
                const float4 b = *(const float4*)&sC[BS1(s, c0)];
                MAX4(m, b);
            }
            float4 f;
            f.x = elu_f(a1[i].x + m.x); f.y = elu_f(a1[i].y + m.y);
            f.z = elu_f(a1[i].z + m.z); f.w = elu_f(a1[i].w + m.w);
            *(float4*)&sB[ROT(q, c0)] = f;
        }
    }
    __syncthreads();

    // ---- Phase7 (P8b): conv2 scores -> sC[q*64+s]; inline norm (1 s per thread) ----
    {
        const int s  = tid & 63;
        const int q0 = (tid >> 6) * 8;     // wave w handles q = 8w..8w+7
        float acc[8];
        #pragma unroll
        for (int i = 0; i < 8; i++) acc[i] = 0.f;
        float nrm = 0.f;
        for (int d0 = 0; d0 < 128; d0 += 4) {
            const float4 f = *(const float4*)&sB[ROT(s, d0)];
            nrm = fmaf(f.x, f.x, nrm); nrm = fmaf(f.y, f.y, nrm);
            nrm = fmaf(f.z, f.z, nrm); nrm = fmaf(f.w, f.w, nrm);
            #pragma unroll
            for (int i = 0; i < 8; i++) {
                const float4 t = *(const float4*)&sA[ROT(q0 + i, d0)];
                acc[i] = fmaf(t.x, f.x, acc[i]); acc[i] = fmaf(t.y, f.y, acc[i]);
                acc[i] = fmaf(t.z, f.z, acc[i]); acc[i] = fmaf(t.w, f.w, acc[i]);
            }
        }
        #pragma unroll
        for (int i = 0; i < 8; i++)
            sC[(q0 + i) * 64 + s] = fmaf(-2.f, acc[i], nrm);
    }
    __syncthreads();

    // ---- Phase8: P8c (top-8 of 64, shfl, regs) + P8d (bsrc2 GEMM -> sA) ----
    unsigned int lo2, hi2;
    {
        const int q = tid >> 3;
        const int j = tid & 7;
        float v[8];
        *(float4*)&v[0] = *(const float4*)&sC[q * 64 + 8 * j];
        *(float4*)&v[4] = *(const float4*)&sC[q * 64 + 8 * j + 4];
        lo2 = 0u; hi2 = 0u;
        #pragma unroll
        for (int r = 0; r < 8; r++) {
            float bv = v[0]; int bs = 8 * j;
            #pragma unroll
            for (int t = 1; t < 8; t++)
                if (v[t] < bv) { bv = v[t]; bs = 8 * j + t; }
            #pragma unroll
            for (int o = 1; o <= 4; o <<= 1) {
                const float ov = __shfl_xor(bv, o, 8);
                const int   os = __shfl_xor(bs, o, 8);
                if (ov < bv || (ov == bv && os < bs)) { bv = ov; bs = os; }
            }
            if (r < 4) lo2 |= (unsigned int)bs << (8 * r);
            else       hi2 |= (unsigned int)bs << (8 * (r - 4));
            #pragma unroll
            for (int t = 0; t < 8; t++)
                if (bs == 8 * j + t) v[t] = INF_F;
        }

        // P8d: bsrc2[s][c] = f1_s @ Wc2_bot -> sA (trk dead after Phase7)
        const int r0 = rg * 4;
        float4 acc[4];
        #pragma unroll
        for (int i = 0; i < 4; i++) acc[i] = make_float4(0.f, 0.f, 0.f, 0.f);
        for (int d0 = 0; d0 < 128; d0 += 4) {
            const float4 w0 = *(const float4*)&W_c2[(128 + d0 + 0) * 128 + c0];
            const float4 w1 = *(const float4*)&W_c2[(128 + d0 + 1) * 128 + c0];
            const float4 w2 = *(const float4*)&W_c2[(128 + d0 + 2) * 128 + c0];
            const float4 w3 = *(const float4*)&W_c2[(128 + d0 + 3) * 128 + c0];
            #pragma unroll
            for (int i = 0; i < 4; i++) {
                const float4 f = *(const float4*)&sB[ROT(r0 + i, d0)];
                FMA4(acc[i], f.x, w0); FMA4(acc[i], f.y, w1);
                FMA4(acc[i], f.z, w2); FMA4(acc[i], f.w, w3);
            }
        }
        #pragma unroll
        for (int i = 0; i < 4; i++)
            *(float4*)&sA[ROT(r0 + i, c0)] = acc[i];
    }
    __syncthreads();

    // ---- Phase9 (P8e): f2 = elu(a2 + max_j bsrc2[idx_j]); partial mean-pool -> sB ----
    {
        const int q0 = rg * 4;
        float4 ps = {0.f, 0.f, 0.f, 0.f};
        #pragma unroll
        for (int i = 0; i < 4; i++) {
            const unsigned int plo = __shfl(lo2, 8 * i + lane_hi);
            const unsigned int phi = __shfl(hi2, 8 * i + lane_hi);
            float4 m = {-INF_F, -INF_F, -INF_F, -INF_F};
            #pragma unroll
            for (int j = 0; j < 8; j++) {
                const int s = (int)(((j < 4) ? (plo >> (8 * j)) : (phi >> (8 * (j - 4)))) & 63u);
                const float4 b = *(const float4*)&sA[ROT(s, c0)];
                MAX4(m, b);
            }
            ps.x += elu_f(a2v[i].x + m.x); ps.y += elu_f(a2v[i].y + m.y);
            ps.z += elu_f(a2v[i].z + m.z); ps.w += elu_f(a2v[i].w + m.w);
        }
        *(float4*)&sB[rg * 128 + c0] = ps;   // f1 dead (consumed by P8d)
    }
    __syncthreads();

    // ---- P9: pooled mean + head (scratch in sB[2048..]) ----
    if (tid < 128) {
        float p = 0.f;
        #pragma unroll
        for (int t = 0; t < 16; t++) p += sB[t * 128 + tid];
        sB[2048 + tid] = p * (1.f / 64.f);
    }
    __syncthreads();
    if (tid < 64) {
        float acc = b_o1[tid];
        for (int d = 0; d < 128; d++) acc = fmaf(sB[2048 + d], W_o1[d * 64 + tid], acc);
        sB[2176 + tid] = elu_f(acc);
    }
    __syncthreads();
    if (tid < 32) {
        float acc = b_o2[tid];
        for (int d = 0; d < 64; d++) acc = fmaf(sB[2176 + d], W_o2[d * 32 + tid], acc);
        sB[2240 + tid] = elu_f(acc);
    }
    __syncthreads();
    if (tid < 4) {
        float acc = b_o3[tid];
        for (int d = 0; d < 32; d++) acc = fmaf(sB[2240 + d], W_o3[d * 4 + tid], acc);
        sB[2272 + tid] = elu_f(acc);
    }
    __syncthreads();
    if (tid == 0) {
        float acc = b_o4[0];
        #pragma unroll
        for (int d = 0; d < 4; d++) acc = fmaf(sB[2272 + d], W_o4[d], acc);
        out[g] = acc;            // output 0: (G,1)
        out[G_ + g] = (float)g;  // output 1: batch = arange(G)
    }
}

extern "C" void kernel_launch(void* const* d_in, const int* in_sizes, int n_in,
                              void* d_out, int out_size, void* d_ws, size_t ws_size,
                              hipStream_t stream) {
    const float* x_sv   = (const float*)d_in[0];
    const float* x_trk  = (const float*)d_in[1];
    const float* W_sv1  = (const float*)d_in[2];
    const float* b_sv1  = (const float*)d_in[3];
    const float* W_sv2  = (const float*)d_in[4];
    const float* b_sv2  = (const float*)d_in[5];
    const float* W_trk1 = (const float*)d_in[6];
    const float* b_trk1 = (const float*)d_in[7];
    const float* W_trk2 = (const float*)d_in[8];
    const float* b_trk2 = (const float*)d_in[9];
    const float* W_c1   = (const float*)d_in[10];
    const float* b_c1   = (const float*)d_in[11];
    const float* W_c2   = (const float*)d_in[12];
    const float* b_c2   = (const float*)d_in[13];
    const float* W_o1   = (const float*)d_in[14];
    const float* b_o1   = (const float*)d_in[15];
    const float* W_o2   = (const float*)d_in[16];
    const float* b_o2   = (const float*)d_in[17];
    const float* W_o3   = (const float*)d_in[18];
    const float* b_o3   = (const float*)d_in[19];
    const float* W_o4   = (const float*)d_in[20];
    const float* b_o4   = (const float*)d_in[21];
    float* out = (float*)d_out;

    const bool use_wd = (ws_size >= 2u * 16384u * sizeof(float)) && d_ws != nullptr;
    float* wdp = (float*)d_ws;

    if (use_wd) {
        prep_wdiff<<<64, 256, 0, stream>>>(W_c1, W_c2, wdp);
        fused_net<true><<<G_, TPB, 0, stream>>>(x_sv, x_trk, W_sv1, b_sv1, W_sv2, b_sv2,
                                                W_trk1, b_trk1, W_trk2, b_trk2,
                                                W_c1, b_c1, W_c2, b_c2,
                                                W_o1, b_o1, W_o2, b_o2, W_o3, b_o3,
                                                W_o4, b_o4, wdp, out);
    } else {
        fused_net<false><<<G_, TPB, 0, stream>>>(x_sv, x_trk, W_sv1, b_sv1, W_sv2, b_sv2,
                                                 W_trk1, b_trk1, W_trk2, b_trk2,
                                                 W_c1, b_c1, W_c2, b_c2,
                                                 W_o1, b_o1, W_o2, b_o2, W_o3, b_o3,
                                                 W_o4, b_o4, (const float*)nullptr, out);
    }
}

// Round 5
// 258.618 us; speedup vs baseline: 2.8268x; 1.2980x over previous
//
#include <hip/hip_runtime.h>

#define G_    1024
#define TPB   512
#define INF_F 3.4e38f

typedef __attribute__((ext_vector_type(8))) short short8;
typedef __attribute__((ext_vector_type(4))) float f32x4;

__device__ __forceinline__ float elu_fast(float x) { return x > 0.f ? x : __expf(x) - 1.f; }
__device__ __forceinline__ float elu_ref(float x)  { return x > 0.f ? x : expm1f(x); }

// Rotated row layouts (rotation multiple of 4 -> float4 stays aligned, 2-way banks)
#define ROT(r, d)    ((r)*128 + (((d) + 4*(r)) & 127))
#define BS1(s, c)    (2048 + (s)*128 + (((c) + 4*(s)) & 127))

#define FMA4(acc_, sc_, wv_) do { (acc_).x = fmaf((sc_),(wv_).x,(acc_).x); \
                                  (acc_).y = fmaf((sc_),(wv_).y,(acc_).y); \
                                  (acc_).z = fmaf((sc_),(wv_).z,(acc_).z); \
                                  (acc_).w = fmaf((sc_),(wv_).w,(acc_).w); } while(0)
#define MAX4(mm_, bb_)       do { (mm_).x = fmaxf((mm_).x,(bb_).x); \
                                  (mm_).y = fmaxf((mm_).y,(bb_).y); \
                                  (mm_).z = fmaxf((mm_).z,(bb_).z); \
                                  (mm_).w = fmaxf((mm_).w,(bb_).w); } while(0)

// 6-term split product: error ~2^-24 relative (fp32-class)
#define MFMA6(acc_, Ah_,Am_,Al_, Bh_,Bm_,Bl_) do { \
  acc_ = __builtin_amdgcn_mfma_f32_16x16x32_bf16(Ah_, Bh_, acc_, 0,0,0); \
  acc_ = __builtin_amdgcn_mfma_f32_16x16x32_bf16(Ah_, Bm_, acc_, 0,0,0); \
  acc_ = __builtin_amdgcn_mfma_f32_16x16x32_bf16(Am_, Bh_, acc_, 0,0,0); \
  acc_ = __builtin_amdgcn_mfma_f32_16x16x32_bf16(Ah_, Bl_, acc_, 0,0,0); \
  acc_ = __builtin_amdgcn_mfma_f32_16x16x32_bf16(Al_, Bh_, acc_, 0,0,0); \
  acc_ = __builtin_amdgcn_mfma_f32_16x16x32_bf16(Am_, Bm_, acc_, 0,0,0); } while(0)

union U8 { unsigned d[4]; short8 v; };

// Split 8 contiguous fp32 (two float4s) into 3 packed bf16 planes (exact residues).
__device__ __forceinline__ void split_frag(const float* p0, const float* p1,
                                           short8& H, short8& M, short8& L) {
    float xs[8];
    *(float4*)&xs[0] = *(const float4*)p0;
    *(float4*)&xs[4] = *(const float4*)p1;
    U8 uh, um, ul;
    #pragma unroll
    for (int k = 0; k < 4; k++) {
        const unsigned u0 = __float_as_uint(xs[2*k]),   h0 = u0 & 0xFFFF0000u;
        const unsigned u1 = __float_as_uint(xs[2*k+1]), h1 = u1 & 0xFFFF0000u;
        const float r10 = xs[2*k]   - __uint_as_float(h0);
        const float r11 = xs[2*k+1] - __uint_as_float(h1);
        const unsigned v0 = __float_as_uint(r10), m0 = v0 & 0xFFFF0000u;
        const unsigned v1 = __float_as_uint(r11), m1 = v1 & 0xFFFF0000u;
        const float r20 = r10 - __uint_as_float(m0);
        const float r21 = r11 - __uint_as_float(m1);
        uh.d[k] = (u0 >> 16) | h1;
        um.d[k] = (v0 >> 16) | m1;
        ul.d[k] = (__float_as_uint(r20) >> 16) | (__float_as_uint(r21) & 0xFFFF0000u);
    }
    H = uh.v; M = um.v; L = ul.v;
}

// ---- prep: split 6 weight matrices into 3 bf16 planes, packed in B-fragment order.
// Consumption: frag elem (lane, j) of tile (ks, ni) = W[ks*32 + (lane>>4)*8 + j][ni*16 + (lane&15)]
// matrices: 0=W_trk2 1=W_sv2 2=Wc1_bot 3=Wd1 4=Wd2 5=Wc2_bot
__global__ void prep_pack(const float* __restrict__ Wtrk2, const float* __restrict__ Wsv2,
                          const float* __restrict__ Wc1,   const float* __restrict__ Wc2,
                          unsigned short* __restrict__ wsu) {
    const int i = blockIdx.x * 256 + threadIdx.x;
    if (i >= 6 * 16384) return;
    const int m = i >> 14;
    const int e = i & 16383;
    const int d = e >> 7, c = e & 127;
    float v;
    switch (m) {
        case 0: v = Wtrk2[e]; break;
        case 1: v = Wsv2[e]; break;
        case 2: v = Wc1[16384 + e]; break;
        case 3: v = Wc1[e] - Wc1[16384 + e]; break;
        case 4: v = Wc2[e] - Wc2[16384 + e]; break;
        default: v = Wc2[16384 + e]; break;
    }
    const unsigned u  = __float_as_uint(v);
    const unsigned hb = u & 0xFFFF0000u;
    const float    r1 = v - __uint_as_float(hb);
    const unsigned u1 = __float_as_uint(r1);
    const unsigned mb = u1 & 0xFFFF0000u;
    const float    r2 = r1 - __uint_as_float(mb);
    const unsigned u2 = __float_as_uint(r2);
    const int ks = d >> 5, kin = d & 31, quad = kin >> 3, j = kin & 7;
    const int ni = c >> 4, n = c & 15, lane = quad * 16 + n;
    const int pos = ((ks * 8 + ni) * 64 + lane) * 8 + j;
    wsu[(m * 3 + 0) * 16384 + pos] = (unsigned short)(u  >> 16);
    wsu[(m * 3 + 1) * 16384 + pos] = (unsigned short)(u1 >> 16);
    wsu[(m * 3 + 2) * 16384 + pos] = (unsigned short)(u2 >> 16);
}

__global__ __launch_bounds__(TPB, 4)
void fused_mfma(const float* __restrict__ x_sv,  const float* __restrict__ x_trk,
                const float* __restrict__ W_sv1, const float* __restrict__ b_sv1,
                const float* __restrict__ b_sv2,
                const float* __restrict__ W_trk1,const float* __restrict__ b_trk1,
                const float* __restrict__ b_trk2,
                const float* __restrict__ b_c1,  const float* __restrict__ b_c2,
                const float* __restrict__ W_o1,  const float* __restrict__ b_o1,
                const float* __restrict__ W_o2,  const float* __restrict__ b_o2,
                const float* __restrict__ W_o3,  const float* __restrict__ b_o3,
                const float* __restrict__ W_o4,  const float* __restrict__ b_o4,
                const unsigned short* __restrict__ wsu,
                float* __restrict__ out)
{
    __shared__ float sA[8192];   // 32 KB : T (rot) -> bsrc2 (rot)
    __shared__ float sB[8192];   // 32 KB : h_trk/h_sv (rot) -> scores1 + pack-handoff -> f1 (rot) -> pool+head
    __shared__ float sC[4096];   // 16 KB : x stage -> sv_emb (rot) + bsrc1 -> scores2 + idx2 handoff
    unsigned* sBu = (unsigned*)sB;
    unsigned* sCu = (unsigned*)sC;

    const int g    = blockIdx.x;
    const int tid  = threadIdx.x;
    const int c128 = tid & 127;
    const int g4   = tid >> 7;
    const int wv   = tid >> 6;          // wave 0..7
    const int lane = tid & 63;
    const int quad = lane >> 4;
    const int ln   = lane & 15;

    // ---- P0: stage inputs
    sC[2048 + tid] = x_trk[(size_t)g * 512 + tid];
    if (tid < 32) sC[2560 + tid] = x_sv[(size_t)g * 32 + tid];
    __syncthreads();

    // ---- P1: trk MLP layer 1 -> h in sB (rot)
    {
        float w[8];
        #pragma unroll
        for (int k = 0; k < 8; k++) w[k] = W_trk1[k * 128 + c128];
        const float b1 = b_trk1[c128];
        #pragma unroll
        for (int i = 0; i < 16; i++) {
            const int r = g4 * 16 + i;
            float xr[8];
            *(float4*)&xr[0] = *(const float4*)&sC[2048 + r * 8];
            *(float4*)&xr[4] = *(const float4*)&sC[2048 + r * 8 + 4];
            float acc = b1;
            #pragma unroll
            for (int k = 0; k < 8; k++) acc = fmaf(xr[k], w[k], acc);
            sB[ROT(r, c128)] = elu_fast(acc);
        }
    }
    __syncthreads();

    // ---- P2 (MFMA): T = relu(h @ W_trk2 + b) -> sA (rot)
    {
        const int mi = wv >> 1, nb = (wv & 1) * 4;
        const int row = mi * 16 + ln;
        f32x4 acc[4];
        #pragma unroll
        for (int t = 0; t < 4; t++) {
            const float bz = b_trk2[(nb + t) * 16 + ln];
            acc[t] = (f32x4){bz, bz, bz, bz};
        }
        #pragma unroll
        for (int ks = 0; ks < 4; ks++) {
            const int k0 = ks * 32 + quad * 8;
            short8 Ah, Am, Al;
            split_frag(&sB[ROT(row, k0)], &sB[ROT(row, k0 + 4)], Ah, Am, Al);
            #pragma unroll
            for (int t = 0; t < 4; t++) {
                const int pos = ((ks * 8 + (nb + t)) * 64 + lane) * 8;
                const short8 Bh = *(const short8*)(wsu + 0 * 16384 + pos);
                const short8 Bm = *(const short8*)(wsu + 1 * 16384 + pos);
                const short8 Bl = *(const short8*)(wsu + 2 * 16384 + pos);
                MFMA6(acc[t], Ah, Am, Al, Bh, Bm, Bl);
            }
        }
        #pragma unroll
        for (int t = 0; t < 4; t++)
            #pragma unroll
            for (int r = 0; r < 4; r++) {
                const int rr = mi * 16 + quad * 4 + r;
                const int cc = (nb + t) * 16 + ln;
                sA[ROT(rr, cc)] = fmaxf(acc[t][r], 0.f);
            }
    }
    __syncthreads();

    // ---- P3: sv MLP layer 1 -> h_sv rows 0..15 in sB (rot)
    {
        const float w0 = W_sv1[c128], w1 = W_sv1[128 + c128];
        const float b1 = b_sv1[c128];
        #pragma unroll
        for (int i = 0; i < 4; i++) {
            const int s = g4 * 4 + i;
            sB[ROT(s, c128)] =
                elu_fast(fmaf(sC[2560 + s * 2 + 1], w1, fmaf(sC[2560 + s * 2], w0, b1)));
        }
    }
    __syncthreads();

    // ---- P3b (MFMA): sv_emb = relu(h_sv @ W_sv2 + b) -> sC rows 0..15 (rot)
    {
        const int ni = wv;
        const float bz = b_sv2[ni * 16 + ln];
        f32x4 acc = (f32x4){bz, bz, bz, bz};
        #pragma unroll
        for (int ks = 0; ks < 4; ks++) {
            const int k0 = ks * 32 + quad * 8;
            short8 Ah, Am, Al;
            split_frag(&sB[ROT(ln, k0)], &sB[ROT(ln, k0 + 4)], Ah, Am, Al);
            const int pos = ((ks * 8 + ni) * 64 + lane) * 8;
            const short8 Bh = *(const short8*)(wsu + (1 * 3 + 0) * 16384 + pos);
            const short8 Bm = *(const short8*)(wsu + (1 * 3 + 1) * 16384 + pos);
            const short8 Bl = *(const short8*)(wsu + (1 * 3 + 2) * 16384 + pos);
            MFMA6(acc, Ah, Am, Al, Bh, Bm, Bl);
        }
        #pragma unroll
        for (int r = 0; r < 4; r++) {
            const int rr = quad * 4 + r;
            const int cc = ni * 16 + ln;
            sC[ROT(rr, cc)] = fmaxf(acc[r], 0.f);
        }
    }
    __syncthreads();

    // ---- PhaseB1 (MFMA): bsrc1 = sv_emb @ Wc1_bot -> sC[2048..] ; then P4 vector scores
    {
        const int ni = wv;
        f32x4 acc = (f32x4){0.f, 0.f, 0.f, 0.f};
        #pragma unroll
        for (int ks = 0; ks < 4; ks++) {
            const int k0 = ks * 32 + quad * 8;
            short8 Ah, Am, Al;
            split_frag(&sC[ROT(ln, k0)], &sC[ROT(ln, k0 + 4)], Ah, Am, Al);
            const int pos = ((ks * 8 + ni) * 64 + lane) * 8;
            const short8 Bh = *(const short8*)(wsu + (2 * 3 + 0) * 16384 + pos);
            const short8 Bm = *(const short8*)(wsu + (2 * 3 + 1) * 16384 + pos);
            const short8 Bl = *(const short8*)(wsu + (2 * 3 + 2) * 16384 + pos);
            MFMA6(acc, Ah, Am, Al, Bh, Bm, Bl);
        }
        #pragma unroll
        for (int r = 0; r < 4; r++) {
            const int rr = quad * 4 + r;
            const int cc = ni * 16 + ln;
            sC[BS1(rr, cc)] = acc[r];
        }
    }
    // P4 (vector, exact): conv1 scores -> sB[q*17+s]
    {
        const int q  = tid >> 3;
        const int s0 = tid & 7;
        float d0a = 0.f, d1a = 0.f, n0 = 0.f, n1 = 0.f;
        for (int d0 = 0; d0 < 128; d0 += 4) {
            const float4 t  = *(const float4*)&sA[ROT(q, d0)];
            const float4 v0 = *(const float4*)&sC[ROT(s0, d0)];
            const float4 v1 = *(const float4*)&sC[ROT(s0 + 8, d0)];
            d0a += t.x * v0.x + t.y * v0.y + t.z * v0.z + t.w * v0.w;
            d1a += t.x * v1.x + t.y * v1.y + t.z * v1.z + t.w * v1.w;
            n0  += v0.x * v0.x + v0.y * v0.y + v0.z * v0.z + v0.w * v0.w;
            n1  += v1.x * v1.x + v1.y * v1.y + v1.z * v1.z + v1.w * v1.w;
        }
        sB[q * 17 + s0]     = fmaf(-2.f, d0a, n0);
        sB[q * 17 + s0 + 8] = fmaf(-2.f, d1a, n1);
    }
    __syncthreads();

    // ---- Phase5: top-8 of 16 (shfl) + handoff packs to sBu[1088+q]
    {
        const int q  = tid >> 3;
        const int s0 = tid & 7;
        float sc0 = sB[q * 17 + s0];
        float sc1 = sB[q * 17 + s0 + 8];
        unsigned pack1 = 0u;
        #pragma unroll
        for (int r = 0; r < 8; r++) {
            float bv = sc0; int bs = s0;
            if (sc1 < bv) { bv = sc1; bs = s0 + 8; }
            #pragma unroll
            for (int o = 1; o <= 4; o <<= 1) {
                const float ov = __shfl_xor(bv, o, 8);
                const int   os = __shfl_xor(bs, o, 8);
                if (ov < bv || (ov == bv && os < bs)) { bv = ov; bs = os; }
            }
            pack1 |= (unsigned)bs << (4 * r);
            if (bs == s0)     sc0 = INF_F;
            if (bs == s0 + 8) sc1 = INF_F;
        }
        if (s0 == 0) sBu[1088 + q] = pack1;
    }
    __syncthreads();

    // ---- Phase6 (MFMA): a1/a2 = T @ Wd1/Wd2 + b ; f1 = elu(a1 + max bsrc1[idx]) -> sB
    f32x4 a2acc[4];
    {
        const int mi = wv >> 1, nb = (wv & 1) * 4;
        const int row = mi * 16 + ln;
        f32x4 a1acc[4];
        #pragma unroll
        for (int t = 0; t < 4; t++) {
            const float bz1 = b_c1[(nb + t) * 16 + ln];
            const float bz2 = b_c2[(nb + t) * 16 + ln];
            a1acc[t] = (f32x4){bz1, bz1, bz1, bz1};
            a2acc[t] = (f32x4){bz2, bz2, bz2, bz2};
        }
        #pragma unroll
        for (int ks = 0; ks < 4; ks++) {
            const int k0 = ks * 32 + quad * 8;
            short8 Ah, Am, Al;
            split_frag(&sA[ROT(row, k0)], &sA[ROT(row, k0 + 4)], Ah, Am, Al);
            #pragma unroll
            for (int t = 0; t < 4; t++) {
                const int pos = ((ks * 8 + (nb + t)) * 64 + lane) * 8;
                {
                    const short8 Bh = *(const short8*)(wsu + (3 * 3 + 0) * 16384 + pos);
                    const short8 Bm = *(const short8*)(wsu + (3 * 3 + 1) * 16384 + pos);
                    const short8 Bl = *(const short8*)(wsu + (3 * 3 + 2) * 16384 + pos);
                    MFMA6(a1acc[t], Ah, Am, Al, Bh, Bm, Bl);
                }
                {
                    const short8 Bh = *(const short8*)(wsu + (4 * 3 + 0) * 16384 + pos);
                    const short8 Bm = *(const short8*)(wsu + (4 * 3 + 1) * 16384 + pos);
                    const short8 Bl = *(const short8*)(wsu + (4 * 3 + 2) * 16384 + pos);
                    MFMA6(a2acc[t], Ah, Am, Al, Bh, Bm, Bl);
                }
            }
        }
        unsigned pk[4];
        #pragma unroll
        for (int r = 0; r < 4; r++) pk[r] = sBu[1088 + mi * 16 + quad * 4 + r];
        __syncthreads();   // all packs read before f1 overwrites sB
        #pragma unroll
        for (int t = 0; t < 4; t++) {
            const int cc = (nb + t) * 16 + ln;
            #pragma unroll
            for (int r = 0; r < 4; r++) {
                const int rr = mi * 16 + quad * 4 + r;
                float mx = -INF_F;
                #pragma unroll
                for (int j = 0; j < 8; j++) {
                    const int s = (int)((pk[r] >> (4 * j)) & 15u);
                    mx = fmaxf(mx, sC[BS1(s, cc)]);
                }
                sB[ROT(rr, cc)] = elu_fast(a1acc[t][r] + mx);   // elu after max (monotone)
            }
        }
    }
    __syncthreads();

    // ---- Phase7 (vector, exact): conv2 scores -> sC[q*64+s]
    {
        const int s  = tid & 63;
        const int q0 = (tid >> 6) * 8;
        float acc[8];
        #pragma unroll
        for (int i = 0; i < 8; i++) acc[i] = 0.f;
        float nrm = 0.f;
        for (int d0 = 0; d0 < 128; d0 += 4) {
            const float4 f = *(const float4*)&sB[ROT(s, d0)];
            nrm = fmaf(f.x, f.x, nrm); nrm = fmaf(f.y, f.y, nrm);
            nrm = fmaf(f.z, f.z, nrm); nrm = fmaf(f.w, f.w, nrm);
            #pragma unroll
            for (int i = 0; i < 8; i++) {
                const float4 t = *(const float4*)&sA[ROT(q0 + i, d0)];
                acc[i] = fmaf(t.x, f.x, acc[i]); acc[i] = fmaf(t.y, f.y, acc[i]);
                acc[i] = fmaf(t.z, f.z, acc[i]); acc[i] = fmaf(t.w, f.w, acc[i]);
            }
        }
        #pragma unroll
        for (int i = 0; i < 8; i++)
            sC[(q0 + i) * 64 + s] = fmaf(-2.f, acc[i], nrm);
    }
    __syncthreads();

    // ---- Phase8a: top-8 of 64 (shfl)
    unsigned lo2, hi2;
    {
        const int q = tid >> 3;
        const int j = tid & 7;
        float v[8];
        *(float4*)&v[0] = *(const float4*)&sC[q * 64 + 8 * j];
        *(float4*)&v[4] = *(const float4*)&sC[q * 64 + 8 * j + 4];
        lo2 = 0u; hi2 = 0u;
        #pragma unroll
        for (int r = 0; r < 8; r++) {
            float bv = v[0]; int bs = 8 * j;
            #pragma unroll
            for (int t = 1; t < 8; t++)
                if (v[t] < bv) { bv = v[t]; bs = 8 * j + t; }
            #pragma unroll
            for (int o = 1; o <= 4; o <<= 1) {
                const float ov = __shfl_xor(bv, o, 8);
                const int   os = __shfl_xor(bs, o, 8);
                if (ov < bv || (ov == bv && os < bs)) { bv = ov; bs = os; }
            }
            if (r < 4) lo2 |= (unsigned)bs << (8 * r);
            else       hi2 |= (unsigned)bs << (8 * (r - 4));
            #pragma unroll
            for (int t = 0; t < 8; t++)
                if (bs == 8 * j + t) v[t] = INF_F;
        }
    }
    __syncthreads();   // all score reads done before handoff overwrites sC rows 0..1

    // ---- Phase8b: idx2 handoff + P8d (MFMA): bsrc2 = f1 @ Wc2_bot -> sA
    if ((tid & 7) == 0) {
        const int q = tid >> 3;
        sCu[2 * q]     = lo2;
        sCu[2 * q + 1] = hi2;
    }
    {
        const int mi = wv >> 1, nb = (wv & 1) * 4;
        const int row = mi * 16 + ln;
        f32x4 acc[4];
        #pragma unroll
        for (int t = 0; t < 4; t++) acc[t] = (f32x4){0.f, 0.f, 0.f, 0.f};
        #pragma unroll
        for (int ks = 0; ks < 4; ks++) {
            const int k0 = ks * 32 + quad * 8;
            short8 Ah, Am, Al;
            split_frag(&sB[ROT(row, k0)], &sB[ROT(row, k0 + 4)], Ah, Am, Al);
            #pragma unroll
            for (int t = 0; t < 4; t++) {
                const int pos = ((ks * 8 + (nb + t)) * 64 + lane) * 8;
                const short8 Bh = *(const short8*)(wsu + (5 * 3 + 0) * 16384 + pos);
                const short8 Bm = *(const short8*)(wsu + (5 * 3 + 1) * 16384 + pos);
                const short8 Bl = *(const short8*)(wsu + (5 * 3 + 2) * 16384 + pos);
                MFMA6(acc[t], Ah, Am, Al, Bh, Bm, Bl);
            }
        }
        #pragma unroll
        for (int t = 0; t < 4; t++)
            #pragma unroll
            for (int r = 0; r < 4; r++) {
                const int rr = mi * 16 + quad * 4 + r;
                const int cc = (nb + t) * 16 + ln;
                sA[ROT(rr, cc)] = acc[t][r];
            }
    }
    __syncthreads();

    // ---- Phase9: f2 = elu(a2 + max bsrc2[idx]) ; pool -> sB[0..511]
    {
        const int mi = wv >> 1, nb = (wv & 1) * 4;
        unsigned plo[4], phi[4];
        #pragma unroll
        for (int r = 0; r < 4; r++) {
            const int rr = mi * 16 + quad * 4 + r;
            plo[r] = sCu[2 * rr];
            phi[r] = sCu[2 * rr + 1];
        }
        float ps[4] = {0.f, 0.f, 0.f, 0.f};
        #pragma unroll
        for (int t = 0; t < 4; t++) {
            const int cc = (nb + t) * 16 + ln;
            #pragma unroll
            for (int r = 0; r < 4; r++) {
                float mx = -INF_F;
                #pragma unroll
                for (int j = 0; j < 8; j++) {
                    const int s = (int)(((j < 4) ? (plo[r] >> (8 * j))
                                                 : (phi[r] >> (8 * (j - 4)))) & 63u);
                    mx = fmaxf(mx, sA[ROT(s, cc)]);
                }
                ps[t] += elu_fast(a2acc[t][r] + mx);
            }
        }
        #pragma unroll
        for (int t = 0; t < 4; t++) {
            ps[t] += __shfl_xor(ps[t], 16, 64);
            ps[t] += __shfl_xor(ps[t], 32, 64);
        }
        if (lane < 16)
            #pragma unroll
            for (int t = 0; t < 4; t++)
                sB[mi * 128 + (nb + t) * 16 + lane] = ps[t];
    }
    __syncthreads();

    // ---- Head
    if (tid < 128) {
        const float p = (sB[tid] + sB[128 + tid] + sB[256 + tid] + sB[384 + tid]) * (1.f / 64.f);
        sB[512 + tid] = p;
    }
    __syncthreads();
    if (tid < 64) {
        float acc = b_o1[tid];
        for (int d = 0; d < 128; d++) acc = fmaf(sB[512 + d], W_o1[d * 64 + tid], acc);
        sB[640 + tid] = elu_fast(acc);
    }
    __syncthreads();
    if (tid < 32) {
        float acc = b_o2[tid];
        for (int d = 0; d < 64; d++) acc = fmaf(sB[640 + d], W_o2[d * 32 + tid], acc);
        sB[704 + tid] = elu_fast(acc);
    }
    __syncthreads();
    if (tid < 4) {
        float acc = b_o3[tid];
        for (int d = 0; d < 32; d++) acc = fmaf(sB[704 + d], W_o3[d * 4 + tid], acc);
        sB[736 + tid] = elu_fast(acc);
    }
    __syncthreads();
    if (tid == 0) {
        float acc = b_o4[0];
        #pragma unroll
        for (int d = 0; d < 4; d++) acc = fmaf(sB[736 + d], W_o4[d], acc);
        out[g] = acc;
        out[G_ + g] = (float)g;
    }
}

// ================= vector fallback (round-4 kernel, inline weight diffs) =================
__global__ __launch_bounds__(TPB, 4)
void fused_vec(const float* __restrict__ x_sv,  const float* __restrict__ x_trk,
               const float* __restrict__ W_sv1, const float* __restrict__ b_sv1,
               const float* __restrict__ W_sv2, const float* __restrict__ b_sv2,
               const float* __restrict__ W_trk1,const float* __restrict__ b_trk1,
               const float* __restrict__ W_trk2,const float* __restrict__ b_trk2,
               const float* __restrict__ W_c1,  const float* __restrict__ b_c1,
               const float* __restrict__ W_c2,  const float* __restrict__ b_c2,
               const float* __restrict__ W_o1,  const float* __restrict__ b_o1,
               const float* __restrict__ W_o2,  const float* __restrict__ b_o2,
               const float* __restrict__ W_o3,  const float* __restrict__ b_o3,
               const float* __restrict__ W_o4,  const float* __restrict__ b_o4,
               float* __restrict__ out)
{
    __shared__ float sA[8192];
    __shared__ float sB[8192];
    __shared__ float sC[4096];
    const int g    = blockIdx.x;
    const int tid  = threadIdx.x;
    const int c128 = tid & 127;
    const int g4   = tid >> 7;
    const int cq   = tid & 31;
    const int c0   = cq * 4;
    const int rg   = tid >> 5;
    const int lane_hi = tid & 32;

    sC[2048 + tid] = x_trk[(size_t)g * 512 + tid];
    if (tid < 32) sC[2560 + tid] = x_sv[(size_t)g * 32 + tid];
    __syncthreads();
    {
        float w[8];
        #pragma unroll
        for (int k = 0; k < 8; k++) w[k] = W_trk1[k * 128 + c128];
        const float b1 = b_trk1[c128];
        #pragma unroll
        for (int i = 0; i < 16; i++) {
            const int r = g4 * 16 + i;
            float acc = b1;
            #pragma unroll
            for (int k = 0; k < 8; k++) acc = fmaf(sC[2048 + r * 8 + k], w[k], acc);
            sB[r * 128 + c128] = elu_ref(acc);
        }
    }
    __syncthreads();
    {
        const int r0 = rg * 4;
        float4 acc[4];
        const float4 bz = *(const float4*)&b_trk2[c0];
        #pragma unroll
        for (int i = 0; i < 4; i++) acc[i] = bz;
        for (int d0 = 0; d0 < 128; d0 += 4) {
            const float4 w0 = *(const float4*)&W_trk2[(d0 + 0) * 128 + c0];
            const float4 w1 = *(const float4*)&W_trk2[(d0 + 1) * 128 + c0];
            const float4 w2 = *(const float4*)&W_trk2[(d0 + 2) * 128 + c0];
            const float4 w3 = *(const float4*)&W_trk2[(d0 + 3) * 128 + c0];
            #pragma unroll
            for (int i = 0; i < 4; i++) {
                const float4 h = *(const float4*)&sB[(r0 + i) * 128 + d0];
                FMA4(acc[i], h.x, w0); FMA4(acc[i], h.y, w1);
                FMA4(acc[i], h.z, w2); FMA4(acc[i], h.w, w3);
            }
        }
        #pragma unroll
        for (int i = 0; i < 4; i++) {
            float4 r;
            r.x = fmaxf(acc[i].x, 0.f); r.y = fmaxf(acc[i].y, 0.f);
            r.z = fmaxf(acc[i].z, 0.f); r.w = fmaxf(acc[i].w, 0.f);
            *(float4*)&sA[ROT(r0 + i, c0)] = r;
        }
    }
    __syncthreads();
    {
        const float w0 = W_sv1[c128], w1 = W_sv1[128 + c128];
        const float b1 = b_sv1[c128];
        #pragma unroll
        for (int i = 0; i < 4; i++) {
            const int s = g4 * 4 + i;
            sB[s * 128 + c128] =
                elu_ref(fmaf(sC[2560 + s * 2 + 1], w1, fmaf(sC[2560 + s * 2], w0, b1)));
        }
    }
    __syncthreads();
    {
        const int s = rg;
        float4 acc = *(const float4*)&b_sv2[c0];
        for (int d0 = 0; d0 < 128; d0 += 4) {
            const float4 w0 = *(const float4*)&W_sv2[(d0 + 0) * 128 + c0];
            const float4 w1 = *(const float4*)&W_sv2[(d0 + 1) * 128 + c0];
            const float4 w2 = *(const float4*)&W_sv2[(d0 + 2) * 128 + c0];
            const float4 w3 = *(const float4*)&W_sv2[(d0 + 3) * 128 + c0];
            const float4 h = *(const float4*)&sB[s * 128 + d0];
            FMA4(acc, h.x, w0); FMA4(acc, h.y, w1);
            FMA4(acc, h.z, w2); FMA4(acc, h.w, w3);
        }
        float4 r;
        r.x = fmaxf(acc.x, 0.f); r.y = fmaxf(acc.y, 0.f);
        r.z = fmaxf(acc.z, 0.f); r.w = fmaxf(acc.w, 0.f);
        *(float4*)&sC[ROT(s, c0)] = r;
    }
    __syncthreads();
    unsigned pack1;
    {
        {
            const int s = rg;
            float4 acc = {0.f, 0.f, 0.f, 0.f};
            for (int d0 = 0; d0 < 128; d0 += 4) {
                const float4 e  = *(const float4*)&sC[ROT(s, d0)];
                const float4 w0 = *(const float4*)&W_c1[(128 + d0 + 0) * 128 + c0];
                const float4 w1 = *(const float4*)&W_c1[(128 + d0 + 1) * 128 + c0];
                const float4 w2 = *(const float4*)&W_c1[(128 + d0 + 2) * 128 + c0];
                const float4 w3 = *(const float4*)&W_c1[(128 + d0 + 3) * 128 + c0];
                FMA4(acc, e.x, w0); FMA4(acc, e.y, w1);
                FMA4(acc, e.z, w2); FMA4(acc, e.w, w3);
            }
            *(float4*)&sC[BS1(s, c0)] = acc;
        }
        const int q  = tid >> 3;
        const int s0 = tid & 7;
        float d0a = 0.f, d1a = 0.f, n0 = 0.f, n1 = 0.f;
        for (int d0 = 0; d0 < 128; d0 += 4) {
            const float4 t  = *(const float4*)&sA[ROT(q, d0)];
            const float4 v0 = *(const float4*)&sC[ROT(s0, d0)];
            const float4 v1 = *(const float4*)&sC[ROT(s0 + 8, d0)];
            d0a += t.x * v0.x + t.y * v0.y + t.z * v0.z + t.w * v0.w;
            d1a += t.x * v1.x + t.y * v1.y + t.z * v1.z + t.w * v1.w;
            n0  += v0.x * v0.x + v0.y * v0.y + v0.z * v0.z + v0.w * v0.w;
            n1  += v1.x * v1.x + v1.y * v1.y + v1.z * v1.z + v1.w * v1.w;
        }
        float sc0 = fmaf(-2.f, d0a, n0);
        float sc1 = fmaf(-2.f, d1a, n1);
        pack1 = 0u;
        #pragma unroll
        for (int r = 0; r < 8; r++) {
            float bv = sc0; int bs = s0;
            if (sc1 < bv) { bv = sc1; bs = s0 + 8; }
            #pragma unroll
            for (int o = 1; o <= 4; o <<= 1) {
                const float ov = __shfl_xor(bv, o, 8);
                const int   os = __shfl_xor(bs, o, 8);
                if (ov < bv || (ov == bv && os < bs)) { bv = ov; bs = os; }
            }
            pack1 |= (unsigned)bs << (4 * r);
            if (bs == s0)     sc0 = INF_F;
            if (bs == s0 + 8) sc1 = INF_F;
        }
    }
    __syncthreads();
    float4 a2v[4];
    {
        const int q0 = rg * 4;
        float4 a1[4];
        const float4 bc1 = *(const float4*)&b_c1[c0];
        const float4 bc2 = *(const float4*)&b_c2[c0];
        #pragma unroll
        for (int i = 0; i < 4; i++) { a1[i] = bc1; a2v[i] = bc2; }
        for (int d0 = 0; d0 < 128; d0 += 4) {
            float4 t[4];
            #pragma unroll
            for (int i = 0; i < 4; i++) t[i] = *(const float4*)&sA[ROT(q0 + i, d0)];
            #pragma unroll
            for (int dj = 0; dj < 4; dj++) {
                float4 wv;
                const float4 wa = *(const float4*)&W_c1[(d0 + dj) * 128 + c0];
                const float4 wb = *(const float4*)&W_c1[(128 + d0 + dj) * 128 + c0];
                wv.x = wa.x - wb.x; wv.y = wa.y - wb.y;
                wv.z = wa.z - wb.z; wv.w = wa.w - wb.w;
                FMA4(a1[0], ((const float*)&t[0])[dj], wv);
                FMA4(a1[1], ((const float*)&t[1])[dj], wv);
                FMA4(a1[2], ((const float*)&t[2])[dj], wv);
                FMA4(a1[3], ((const float*)&t[3])[dj], wv);
            }
            #pragma unroll
            for (int dj = 0; dj < 4; dj++) {
                float4 wv;
                const float4 wa = *(const float4*)&W_c2[(d0 + dj) * 128 + c0];
                const float4 wb = *(const float4*)&W_c2[(128 + d0 + dj) * 128 + c0];
                wv.x = wa.x - wb.x; wv.y = wa.y - wb.y;
                wv.z = wa.z - wb.z; wv.w = wa.w - wb.w;
                FMA4(a2v[0], ((const float*)&t[0])[dj], wv);
                FMA4(a2v[1], ((const float*)&t[1])[dj], wv);
                FMA4(a2v[2], ((const float*)&t[2])[dj], wv);
                FMA4(a2v[3], ((const float*)&t[3])[dj], wv);
            }
        }
        #pragma unroll
        for (int i = 0; i < 4; i++) {
            const int q = q0 + i;
            const unsigned pk = __shfl(pack1, 8 * i + lane_hi);
            float4 m = {-INF_F, -INF_F, -INF_F, -INF_F};
            #pragma unroll
            for (int j = 0; j < 8; j++) {
                const int s = (int)((pk >> (4 * j)) & 15u);
                const float4 b = *(const float4*)&sC[BS1(s, c0)];
                MAX4(m, b);
            }
            float4 f;
            f.x = elu_ref(a1[i].x + m.x); f.y = elu_ref(a1[i].y + m.y);
            f.z = elu_ref(a1[i].z + m.z); f.w = elu_ref(a1[i].w + m.w);
            *(float4*)&sB[ROT(q, c0)] = f;
        }
    }
    __syncthreads();
    {
        const int s  = tid & 63;
        const int q0 = (tid >> 6) * 8;
        float acc[8];
        #pragma unroll
        for (int i = 0; i < 8; i++) acc[i] = 0.f;
        float nrm = 0.f;
        for (int d0 = 0; d0 < 128; d0 += 4) {
            const float4 f = *(const float4*)&sB[ROT(s, d0)];
            nrm = fmaf(f.x, f.x, nrm); nrm = fmaf(f.y, f.y, nrm);
            nrm = fmaf(f.z, f.z, nrm); nrm = fmaf(f.w, f.w, nrm);
            #pragma unroll
            for (int i = 0; i < 8; i++) {
                const float4 t = *(const float4*)&sA[ROT(q0 + i, d0)];
                acc[i] = fmaf(t.x, f.x, acc[i]); acc[i] = fmaf(t.y, f.y, acc[i]);
                acc[i] = fmaf(t.z, f.z, acc[i]); acc[i] = fmaf(t.w, f.w, acc[i]);
            }
        }
        #pragma unroll
        for (int i = 0; i < 8; i++)
            sC[(q0 + i) * 64 + s] = fmaf(-2.f, acc[i], nrm);
    }
    __syncthreads();
    unsigned lo2, hi2;
    {
        const int q = tid >> 3;
        const int j = tid & 7;
        float v[8];
        *(float4*)&v[0] = *(const float4*)&sC[q * 64 + 8 * j];
        *(float4*)&v[4] = *(const float4*)&sC[q * 64 + 8 * j + 4];
        lo2 = 0u; hi2 = 0u;
        #pragma unroll
        for (int r = 0; r < 8; r++) {
            float bv = v[0]; int bs = 8 * j;
            #pragma unroll
            for (int t = 1; t < 8; t++)
                if (v[t] < bv) { bv = v[t]; bs = 8 * j + t; }
            #pragma unroll
            for (int o = 1; o <= 4; o <<= 1) {
                const float ov = __shfl_xor(bv, o, 8);
                const int   os = __shfl_xor(bs, o, 8);
                if (ov < bv || (ov == bv && os < bs)) { bv = ov; bs = os; }
            }
            if (r < 4) lo2 |= (unsigned)bs << (8 * r);
            else       hi2 |= (unsigned)bs << (8 * (r - 4));
            #pragma unroll
            for (int t = 0; t < 8; t++)
                if (bs == 8 * j + t) v[t] = INF_F;
        }
        const int r0 = rg * 4;
        float4 acc[4];
        #pragma unroll
        for (int i = 0; i < 4; i++) acc[i] = make_float4(0.f, 0.f, 0.f, 0.f);
        for (int d0 = 0; d0 < 128; d0 += 4) {
            const float4 w0 = *(const float4*)&W_c2[(128 + d0 + 0) * 128 + c0];
            const float4 w1 = *(const float4*)&W_c2[(128 + d0 + 1) * 128 + c0];
            const float4 w2 = *(const float4*)&W_c2[(128 + d0 + 2) * 128 + c0];
            const float4 w3 = *(const float4*)&W_c2[(128 + d0 + 3) * 128 + c0];
            #pragma unroll
            for (int i = 0; i < 4; i++) {
                const float4 f = *(const float4*)&sB[ROT(r0 + i, d0)];
                FMA4(acc[i], f.x, w0); FMA4(acc[i], f.y, w1);
                FMA4(acc[i], f.z, w2); FMA4(acc[i], f.w, w3);
            }
        }
        #pragma unroll
        for (int i = 0; i < 4; i++)
            *(float4*)&sA[ROT(r0 + i, c0)] = acc[i];
    }
    __syncthreads();
    {
        const int q0 = rg * 4;
        float4 ps = {0.f, 0.f, 0.f, 0.f};
        #pragma unroll
        for (int i = 0; i < 4; i++) {
            const unsigned plo = __shfl(lo2, 8 * i + lane_hi);
            const unsigned phi = __shfl(hi2, 8 * i + lane_hi);
            float4 m = {-INF_F, -INF_F, -INF_F, -INF_F};
            #pragma unroll
            for (int j = 0; j < 8; j++) {
                const int s = (int)(((j < 4) ? (plo >> (8 * j)) : (phi >> (8 * (j - 4)))) & 63u);
                const float4 b = *(const float4*)&sA[ROT(s, c0)];
                MAX4(m, b);
            }
            ps.x += elu_ref(a2v[i].x + m.x); ps.y += elu_ref(a2v[i].y + m.y);
            ps.z += elu_ref(a2v[i].z + m.z); ps.w += elu_ref(a2v[i].w + m.w);
        }
        *(float4*)&sB[rg * 128 + c0] = ps;
    }
    __syncthreads();
    if (tid < 128) {
        float p = 0.f;
        #pragma unroll
        for (int t = 0; t < 16; t++) p += sB[t * 128 + tid];
        sB[2048 + tid] = p * (1.f / 64.f);
    }
    __syncthreads();
    if (tid < 64) {
        float acc = b_o1[tid];
        for (int d = 0; d < 128; d++) acc = fmaf(sB[2048 + d], W_o1[d * 64 + tid], acc);
        sB[2176 + tid] = elu_ref(acc);
    }
    __syncthreads();
    if (tid < 32) {
        float acc = b_o2[tid];
        for (int d = 0; d < 64; d++) acc = fmaf(sB[2176 + d], W_o2[d * 32 + tid], acc);
        sB[2240 + tid] = elu_ref(acc);
    }
    __syncthreads();
    if (tid < 4) {
        float acc = b_o3[tid];
        for (int d = 0; d < 32; d++) acc = fmaf(sB[2240 + d], W_o3[d * 4 + tid], acc);
        sB[2272 + tid] = elu_ref(acc);
    }
    __syncthreads();
    if (tid == 0) {
        float acc = b_o4[0];
        #pragma unroll
        for (int d = 0; d < 4; d++) acc = fmaf(sB[2272 + d], W_o4[d], acc);
        out[g] = acc;
        out[G_ + g] = (float)g;
    }
}

extern "C" void kernel_launch(void* const* d_in, const int* in_sizes, int n_in,
                              void* d_out, int out_size, void* d_ws, size_t ws_size,
                              hipStream_t stream) {
    const float* x_sv   = (const float*)d_in[0];
    const float* x_trk  = (const float*)d_in[1];
    const float* W_sv1  = (const float*)d_in[2];
    const float* b_sv1  = (const float*)d_in[3];
    const float* W_sv2  = (const float*)d_in[4];
    const float* b_sv2  = (const float*)d_in[5];
    const float* W_trk1 = (const float*)d_in[6];
    const float* b_trk1 = (const float*)d_in[7];
    const float* W_trk2 = (const float*)d_in[8];
    const float* b_trk2 = (const float*)d_in[9];
    const float* W_c1   = (const float*)d_in[10];
    const float* b_c1   = (const float*)d_in[11];
    const float* W_c2   = (const float*)d_in[12];
    const float* b_c2   = (const float*)d_in[13];
    const float* W_o1   = (const float*)d_in[14];
    const float* b_o1   = (const float*)d_in[15];
    const float* W_o2   = (const float*)d_in[16];
    const float* b_o2   = (const float*)d_in[17];
    const float* W_o3   = (const float*)d_in[18];
    const float* b_o3   = (const float*)d_in[19];
    const float* W_o4   = (const float*)d_in[20];
    const float* b_o4   = (const float*)d_in[21];
    float* out = (float*)d_out;

    const size_t WS_NEED = (size_t)6 * 3 * 16384 * sizeof(unsigned short); // 576 KB
    if (ws_size >= WS_NEED && d_ws != nullptr) {
        unsigned short* wsu = (unsigned short*)d_ws;
        prep_pack<<<384, 256, 0, stream>>>(W_trk2, W_sv2, W_c1, W_c2, wsu);
        fused_mfma<<<G_, TPB, 0, stream>>>(x_sv, x_trk, W_sv1, b_sv1, b_sv2,
                                           W_trk1, b_trk1, b_trk2, b_c1, b_c2,
                                           W_o1, b_o1, W_o2, b_o2, W_o3, b_o3,
                                           W_o4, b_o4, wsu, out);
    } else {
        fused_vec<<<G_, TPB, 0, stream>>>(x_sv, x_trk, W_sv1, b_sv1, W_sv2, b_sv2,
                                          W_trk1, b_trk1, W_trk2, b_trk2,
                                          W_c1, b_c1, W_c2, b_c2,
                                          W_o1, b_o1, W_o2, b_o2, W_o3, b_o3,
                                          W_o4, b_o4, out);
    }
}

// Round 6
// 249.466 us; speedup vs baseline: 2.9305x; 1.0367x over previous
//
#include <hip/hip_runtime.h>

#define G_    1024
#define TPB   512
#define INF_F 3.4e38f

typedef __attribute__((ext_vector_type(8))) short short8;
typedef __attribute__((ext_vector_type(4))) float f32x4;

__device__ __forceinline__ float elu_fast(float x) { return x > 0.f ? x : __expf(x) - 1.f; }
__device__ __forceinline__ float elu_ref(float x)  { return x > 0.f ? x : expm1f(x); }

// Rotated row layouts (rotation multiple of 4 -> float4 stays aligned, 2-way banks)
#define ROT(r, d)    ((r)*128 + (((d) + 4*(r)) & 127))
#define BS1(s, c)    (2048 + (s)*128 + (((c) + 4*(s)) & 127))

#define FMA4(acc_, sc_, wv_) do { (acc_).x = fmaf((sc_),(wv_).x,(acc_).x); \
                                  (acc_).y = fmaf((sc_),(wv_).y,(acc_).y); \
                                  (acc_).z = fmaf((sc_),(wv_).z,(acc_).z); \
                                  (acc_).w = fmaf((sc_),(wv_).w,(acc_).w); } while(0)
#define MAX4(mm_, bb_)       do { (mm_).x = fmaxf((mm_).x,(bb_).x); \
                                  (mm_).y = fmaxf((mm_).y,(bb_).y); \
                                  (mm_).z = fmaxf((mm_).z,(bb_).z); \
                                  (mm_).w = fmaxf((mm_).w,(bb_).w); } while(0)

// 6-term split product: error ~2^-24 relative (fp32-class)
#define MFMA6(acc_, Ah_,Am_,Al_, Bh_,Bm_,Bl_) do { \
  acc_ = __builtin_amdgcn_mfma_f32_16x16x32_bf16(Ah_, Bh_, acc_, 0,0,0); \
  acc_ = __builtin_amdgcn_mfma_f32_16x16x32_bf16(Ah_, Bm_, acc_, 0,0,0); \
  acc_ = __builtin_amdgcn_mfma_f32_16x16x32_bf16(Am_, Bh_, acc_, 0,0,0); \
  acc_ = __builtin_amdgcn_mfma_f32_16x16x32_bf16(Ah_, Bl_, acc_, 0,0,0); \
  acc_ = __builtin_amdgcn_mfma_f32_16x16x32_bf16(Al_, Bh_, acc_, 0,0,0); \
  acc_ = __builtin_amdgcn_mfma_f32_16x16x32_bf16(Am_, Bm_, acc_, 0,0,0); } while(0)

union U8 { unsigned d[4]; short8 v; };

// Split 8 contiguous fp32 (two float4s) into 3 packed bf16 planes (exact residues).
__device__ __forceinline__ void split_frag(const float* p0, const float* p1,
                                           short8& H, short8& M, short8& L) {
    float xs[8];
    *(float4*)&xs[0] = *(const float4*)p0;
    *(float4*)&xs[4] = *(const float4*)p1;
    U8 uh, um, ul;
    #pragma unroll
    for (int k = 0; k < 4; k++) {
        const unsigned u0 = __float_as_uint(xs[2*k]),   h0 = u0 & 0xFFFF0000u;
        const unsigned u1 = __float_as_uint(xs[2*k+1]), h1 = u1 & 0xFFFF0000u;
        const float r10 = xs[2*k]   - __uint_as_float(h0);
        const float r11 = xs[2*k+1] - __uint_as_float(h1);
        const unsigned v0 = __float_as_uint(r10), m0 = v0 & 0xFFFF0000u;
        const unsigned v1 = __float_as_uint(r11), m1 = v1 & 0xFFFF0000u;
        const float r20 = r10 - __uint_as_float(m0);
        const float r21 = r11 - __uint_as_float(m1);
        uh.d[k] = (u0 >> 16) | h1;
        um.d[k] = (v0 >> 16) | m1;
        ul.d[k] = (__float_as_uint(r20) >> 16) | (__float_as_uint(r21) & 0xFFFF0000u);
    }
    H = uh.v; M = um.v; L = ul.v;
}

// prep: split 6 weight matrices into 3 bf16 planes, packed in B-fragment order.
// Output-indexed so the 2B stores are coalesced.
// matrices: 0=W_trk2 1=W_sv2 2=Wc1_bot 3=Wd1 4=Wd2 5=Wc2_bot
__global__ void prep_pack(const float* __restrict__ Wtrk2, const float* __restrict__ Wsv2,
                          const float* __restrict__ Wc1,   const float* __restrict__ Wc2,
                          unsigned short* __restrict__ wsu) {
    const int o = blockIdx.x * 256 + threadIdx.x;
    if (o >= 6 * 16384) return;
    const int m = o >> 14, pos = o & 16383;
    const int j = pos & 7, lane = (pos >> 3) & 63, tile = pos >> 9;
    const int ks = tile >> 3, ni = tile & 7;
    const int d = ks * 32 + (lane >> 4) * 8 + j;
    const int c = ni * 16 + (lane & 15);
    const int e = d * 128 + c;
    float v;
    switch (m) {
        case 0: v = Wtrk2[e]; break;
        case 1: v = Wsv2[e]; break;
        case 2: v = Wc1[16384 + e]; break;
        case 3: v = Wc1[e] - Wc1[16384 + e]; break;
        case 4: v = Wc2[e] - Wc2[16384 + e]; break;
        default: v = Wc2[16384 + e]; break;
    }
    const unsigned u  = __float_as_uint(v);
    const unsigned hb = u & 0xFFFF0000u;
    const float    r1 = v - __uint_as_float(hb);
    const unsigned u1 = __float_as_uint(r1);
    const unsigned mb = u1 & 0xFFFF0000u;
    const float    r2 = r1 - __uint_as_float(mb);
    const unsigned u2 = __float_as_uint(r2);
    wsu[(m * 3 + 0) * 16384 + pos] = (unsigned short)(u  >> 16);
    wsu[(m * 3 + 1) * 16384 + pos] = (unsigned short)(u1 >> 16);
    wsu[(m * 3 + 2) * 16384 + pos] = (unsigned short)(u2 >> 16);
}

#define LOADB(Bh_,Bm_,Bl_, m_, pos_) do { \
    Bh_ = *(const short8*)(wsu + ((m_) * 3 + 0) * 16384 + (pos_)); \
    Bm_ = *(const short8*)(wsu + ((m_) * 3 + 1) * 16384 + (pos_)); \
    Bl_ = *(const short8*)(wsu + ((m_) * 3 + 2) * 16384 + (pos_)); } while(0)

__global__ __launch_bounds__(TPB, 4)
void fused_mfma(const float* __restrict__ x_sv,  const float* __restrict__ x_trk,
                const float* __restrict__ W_sv1, const float* __restrict__ b_sv1,
                const float* __restrict__ b_sv2,
                const float* __restrict__ W_trk1,const float* __restrict__ b_trk1,
                const float* __restrict__ b_trk2,
                const float* __restrict__ b_c1,  const float* __restrict__ b_c2,
                const float* __restrict__ W_o1,  const float* __restrict__ b_o1,
                const float* __restrict__ W_o2,  const float* __restrict__ b_o2,
                const float* __restrict__ W_o3,  const float* __restrict__ b_o3,
                const float* __restrict__ W_o4,  const float* __restrict__ b_o4,
                const unsigned short* __restrict__ wsu,
                float* __restrict__ out)
{
    __shared__ float sA[8192];   // 32 KB : T (rot) -> bsrc2 (rot)
    __shared__ float sB[8192];   // 32 KB : h_trk/h_sv (rot) + svnorm -> scores1+packs -> f1 (rot) -> pool+head
    __shared__ float sC[4096];   // 16 KB : x stage + sv_emb (rot) + bsrc1 -> f1norm + scores2 + idx2
    unsigned* sBu = (unsigned*)sB;
    unsigned* sCu = (unsigned*)sC;

    const int g    = blockIdx.x;
    const int tid  = threadIdx.x;
    const int c128 = tid & 127;
    const int g4   = tid >> 7;
    const int wv   = tid >> 6;          // wave 0..7
    const int lane = tid & 63;
    const int quad = lane >> 4;
    const int ln   = lane & 15;

    // ---- P0: stage inputs
    sC[2048 + tid] = x_trk[(size_t)g * 512 + tid];
    if (tid < 32) sC[2560 + tid] = x_sv[(size_t)g * 32 + tid];
    __syncthreads();

    // ---- P1: trk MLP layer 1 -> h in sB (rot)
    {
        float w[8];
        #pragma unroll
        for (int k = 0; k < 8; k++) w[k] = W_trk1[k * 128 + c128];
        const float b1 = b_trk1[c128];
        #pragma unroll
        for (int i = 0; i < 16; i++) {
            const int r = g4 * 16 + i;
            float xr[8];
            *(float4*)&xr[0] = *(const float4*)&sC[2048 + r * 8];
            *(float4*)&xr[4] = *(const float4*)&sC[2048 + r * 8 + 4];
            float acc = b1;
            #pragma unroll
            for (int k = 0; k < 8; k++) acc = fmaf(xr[k], w[k], acc);
            sB[ROT(r, c128)] = elu_fast(acc);
        }
    }
    __syncthreads();

    // ---- P2 (MFMA): T = relu(h @ W_trk2 + b) -> sA (rot)
    {
        const int mi = wv >> 1, nb = (wv & 1) * 4;
        const int row = mi * 16 + ln;
        f32x4 acc[4];
        #pragma unroll
        for (int t = 0; t < 4; t++) {
            const float bz = b_trk2[(nb + t) * 16 + ln];
            acc[t] = (f32x4){bz, bz, bz, bz};
        }
        #pragma unroll
        for (int ks = 0; ks < 4; ks++) {
            const int k0 = ks * 32 + quad * 8;
            short8 Ah, Am, Al;
            split_frag(&sB[ROT(row, k0)], &sB[ROT(row, k0 + 4)], Ah, Am, Al);
            #pragma unroll
            for (int t = 0; t < 4; t++) {
                const int pos = ((ks * 8 + (nb + t)) * 64 + lane) * 8;
                short8 Bh, Bm, Bl;
                LOADB(Bh, Bm, Bl, 0, pos);
                MFMA6(acc[t], Ah, Am, Al, Bh, Bm, Bl);
            }
        }
        #pragma unroll
        for (int t = 0; t < 4; t++)
            #pragma unroll
            for (int r = 0; r < 4; r++)
                sA[ROT(mi * 16 + quad * 4 + r, (nb + t) * 16 + ln)] = fmaxf(acc[t][r], 0.f);
    }
    __syncthreads();

    // ---- P3: sv MLP layer 1 -> h_sv rows 0..15 in sB (rot)
    {
        const float w0 = W_sv1[c128], w1 = W_sv1[128 + c128];
        const float b1 = b_sv1[c128];
        #pragma unroll
        for (int i = 0; i < 4; i++) {
            const int s = g4 * 4 + i;
            sB[ROT(s, c128)] =
                elu_fast(fmaf(sC[2560 + s * 2 + 1], w1, fmaf(sC[2560 + s * 2], w0, b1)));
        }
    }
    __syncthreads();

    // ---- P3b (MFMA): sv_emb -> sC rows 0..15 (rot); per-wave col-partial norms -> sB[2048+]
    {
        const int ni = wv;
        const float bz = b_sv2[ni * 16 + ln];
        f32x4 acc = (f32x4){bz, bz, bz, bz};
        #pragma unroll
        for (int ks = 0; ks < 4; ks++) {
            const int k0 = ks * 32 + quad * 8;
            short8 Ah, Am, Al;
            split_frag(&sB[ROT(ln, k0)], &sB[ROT(ln, k0 + 4)], Ah, Am, Al);
            const int pos = ((ks * 8 + ni) * 64 + lane) * 8;
            short8 Bh, Bm, Bl;
            LOADB(Bh, Bm, Bl, 1, pos);
            MFMA6(acc, Ah, Am, Al, Bh, Bm, Bl);
        }
        #pragma unroll
        for (int r = 0; r < 4; r++) {
            const float v = fmaxf(acc[r], 0.f);
            sC[ROT(quad * 4 + r, ni * 16 + ln)] = v;
            float p = v * v;
            #pragma unroll
            for (int o = 1; o <= 8; o <<= 1) p += __shfl_xor(p, o, 16);
            if (ln == 0) sB[2048 + ni * 16 + quad * 4 + r] = p;
        }
    }
    __syncthreads();

    // ---- B1 (MFMA): bsrc1 = sv @ Wc1_bot -> sC[2048..]; P4 (MFMA, waves 0..3): scores1 -> sB
    {
        const int ni = wv;
        const bool doP4 = (wv < 4);
        f32x4 accB = (f32x4){0.f, 0.f, 0.f, 0.f};
        f32x4 accS = (f32x4){0.f, 0.f, 0.f, 0.f};
        #pragma unroll
        for (int ks = 0; ks < 4; ks++) {
            const int k0 = ks * 32 + quad * 8;
            short8 Sh, Sm, Sl;   // sv fragment: A for B1, B for P4 (same layout)
            split_frag(&sC[ROT(ln, k0)], &sC[ROT(ln, k0 + 4)], Sh, Sm, Sl);
            const int pos = ((ks * 8 + ni) * 64 + lane) * 8;
            short8 Bh, Bm, Bl;
            LOADB(Bh, Bm, Bl, 2, pos);
            MFMA6(accB, Sh, Sm, Sl, Bh, Bm, Bl);
            if (doP4) {
                const int row = wv * 16 + ln;   // T row (mi = wv)
                short8 Th, Tm, Tl;
                split_frag(&sA[ROT(row, k0)], &sA[ROT(row, k0 + 4)], Th, Tm, Tl);
                MFMA6(accS, Th, Tm, Tl, Sh, Sm, Sl);
            }
        }
        #pragma unroll
        for (int r = 0; r < 4; r++)
            sC[BS1(quad * 4 + r, ni * 16 + ln)] = accB[r];
        if (doP4) {
            float nsv = 0.f;
            #pragma unroll
            for (int p = 0; p < 8; p++) nsv += sB[2048 + p * 16 + ln];
            #pragma unroll
            for (int r = 0; r < 4; r++)
                sB[(wv * 16 + quad * 4 + r) * 17 + ln] = fmaf(-2.f, accS[r], nsv);
        }
    }
    __syncthreads();

    // ---- topk1: top-8 of 16 (shfl) -> packs sBu[1088+q]
    {
        const int q  = tid >> 3;
        const int s0 = tid & 7;
        float sc0 = sB[q * 17 + s0];
        float sc1 = sB[q * 17 + s0 + 8];
        unsigned pack1 = 0u;
        #pragma unroll
        for (int r = 0; r < 8; r++) {
            float bv = sc0; int bs = s0;
            if (sc1 < bv) { bv = sc1; bs = s0 + 8; }
            #pragma unroll
            for (int o = 1; o <= 4; o <<= 1) {
                const float ov = __shfl_xor(bv, o, 8);
                const int   os = __shfl_xor(bs, o, 8);
                if (ov < bv || (ov == bv && os < bs)) { bv = ov; bs = os; }
            }
            pack1 |= (unsigned)bs << (4 * r);
            if (bs == s0)     sc0 = INF_F;
            if (bs == s0 + 8) sc1 = INF_F;
        }
        if (s0 == 0) sBu[1088 + q] = pack1;
    }
    __syncthreads();

    // ---- Phase6 (MFMA): a1/a2 = T @ Wd1/Wd2 + b ; f1 = elu(a1 + max bsrc1[idx]) -> sB ;
    //      f1 norm partials -> sC[0..127]
    f32x4 a2acc[4];
    {
        const int mi = wv >> 1, nb = (wv & 1) * 4;
        const int row = mi * 16 + ln;
        f32x4 a1acc[4];
        #pragma unroll
        for (int t = 0; t < 4; t++) {
            const float bz1 = b_c1[(nb + t) * 16 + ln];
            const float bz2 = b_c2[(nb + t) * 16 + ln];
            a1acc[t] = (f32x4){bz1, bz1, bz1, bz1};
            a2acc[t] = (f32x4){bz2, bz2, bz2, bz2};
        }
        #pragma unroll
        for (int ks = 0; ks < 4; ks++) {
            const int k0 = ks * 32 + quad * 8;
            short8 Ah, Am, Al;
            split_frag(&sA[ROT(row, k0)], &sA[ROT(row, k0 + 4)], Ah, Am, Al);
            #pragma unroll
            for (int t = 0; t < 4; t++) {
                const int pos = ((ks * 8 + (nb + t)) * 64 + lane) * 8;
                short8 Bh, Bm, Bl;
                LOADB(Bh, Bm, Bl, 3, pos);
                MFMA6(a1acc[t], Ah, Am, Al, Bh, Bm, Bl);
                LOADB(Bh, Bm, Bl, 4, pos);
                MFMA6(a2acc[t], Ah, Am, Al, Bh, Bm, Bl);
            }
        }
        unsigned pk[4];
        #pragma unroll
        for (int r = 0; r < 4; r++) pk[r] = sBu[1088 + mi * 16 + quad * 4 + r];
        __syncthreads();   // packs read before f1 overwrites sB
        float np[4] = {0.f, 0.f, 0.f, 0.f};
        #pragma unroll
        for (int t = 0; t < 4; t++) {
            const int cc = (nb + t) * 16 + ln;
            #pragma unroll
            for (int r = 0; r < 4; r++) {
                float mx = -INF_F;
                #pragma unroll
                for (int j = 0; j < 8; j++) {
                    const int s = (int)((pk[r] >> (4 * j)) & 15u);
                    mx = fmaxf(mx, sC[BS1(s, cc)]);
                }
                const float f = elu_fast(a1acc[t][r] + mx);
                sB[ROT(mi * 16 + quad * 4 + r, cc)] = f;
                np[r] = fmaf(f, f, np[r]);
            }
        }
        #pragma unroll
        for (int r = 0; r < 4; r++) {
            #pragma unroll
            for (int o = 1; o <= 8; o <<= 1) np[r] += __shfl_xor(np[r], o, 16);
            if (ln == 0) sC[(wv & 1) * 64 + mi * 16 + quad * 4 + r] = np[r];
        }
    }
    __syncthreads();

    // ---- Phase7 (MFMA): scores2[q][s] = n_s - 2 T_q . f1_s -> sC[q*64+s]
    {
        const int mi = wv >> 1, nia = (wv & 1) * 2;
        const int row = mi * 16 + ln;
        float ns[2];
        #pragma unroll
        for (int u = 0; u < 2; u++) {
            const int s = (nia + u) * 16 + ln;
            ns[u] = sC[s] + sC[64 + s];
        }
        __syncthreads();   // norms read before scores overwrite sC
        f32x4 acc[2];
        acc[0] = (f32x4){0.f, 0.f, 0.f, 0.f};
        acc[1] = (f32x4){0.f, 0.f, 0.f, 0.f};
        #pragma unroll
        for (int ks = 0; ks < 4; ks++) {
            const int k0 = ks * 32 + quad * 8;
            short8 Ah, Am, Al;
            split_frag(&sA[ROT(row, k0)], &sA[ROT(row, k0 + 4)], Ah, Am, Al);
            #pragma unroll
            for (int u = 0; u < 2; u++) {
                const int srow = (nia + u) * 16 + ln;
                short8 Bh, Bm, Bl;
                split_frag(&sB[ROT(srow, k0)], &sB[ROT(srow, k0 + 4)], Bh, Bm, Bl);
                MFMA6(acc[u], Ah, Am, Al, Bh, Bm, Bl);
            }
        }
        #pragma unroll
        for (int u = 0; u < 2; u++) {
            const int s = (nia + u) * 16 + ln;
            #pragma unroll
            for (int r = 0; r < 4; r++)
                sC[(mi * 16 + quad * 4 + r) * 64 + s] = fmaf(-2.f, acc[u][r], ns[u]);
        }
    }
    __syncthreads();

    // ---- topk2: top-8 of 64 (shfl)
    unsigned lo2, hi2;
    {
        const int q = tid >> 3;
        const int j = tid & 7;
        float v[8];
        *(float4*)&v[0] = *(const float4*)&sC[q * 64 + 8 * j];
        *(float4*)&v[4] = *(const float4*)&sC[q * 64 + 8 * j + 4];
        lo2 = 0u; hi2 = 0u;
        #pragma unroll
        for (int r = 0; r < 8; r++) {
            float bv = v[0]; int bs = 8 * j;
            #pragma unroll
            for (int t = 1; t < 8; t++)
                if (v[t] < bv) { bv = v[t]; bs = 8 * j + t; }
            #pragma unroll
            for (int o = 1; o <= 4; o <<= 1) {
                const float ov = __shfl_xor(bv, o, 8);
                const int   os = __shfl_xor(bs, o, 8);
                if (ov < bv || (ov == bv && os < bs)) { bv = ov; bs = os; }
            }
            if (r < 4) lo2 |= (unsigned)bs << (8 * r);
            else       hi2 |= (unsigned)bs << (8 * (r - 4));
            #pragma unroll
            for (int t = 0; t < 8; t++)
                if (bs == 8 * j + t) v[t] = INF_F;
        }
    }
    __syncthreads();

    // ---- idx2 handoff + P8d (MFMA): bsrc2 = f1 @ Wc2_bot -> sA
    if ((tid & 7) == 0) {
        const int q = tid >> 3;
        sCu[2 * q]     = lo2;
        sCu[2 * q + 1] = hi2;
    }
    {
        const int mi = wv >> 1, nb = (wv & 1) * 4;
        const int row = mi * 16 + ln;
        f32x4 acc[4];
        #pragma unroll
        for (int t = 0; t < 4; t++) acc[t] = (f32x4){0.f, 0.f, 0.f, 0.f};
        #pragma unroll
        for (int ks = 0; ks < 4; ks++) {
            const int k0 = ks * 32 + quad * 8;
            short8 Ah, Am, Al;
            split_frag(&sB[ROT(row, k0)], &sB[ROT(row, k0 + 4)], Ah, Am, Al);
            #pragma unroll
            for (int t = 0; t < 4; t++) {
                const int pos = ((ks * 8 + (nb + t)) * 64 + lane) * 8;
                short8 Bh, Bm, Bl;
                LOADB(Bh, Bm, Bl, 5, pos);
                MFMA6(acc[t], Ah, Am, Al, Bh, Bm, Bl);
            }
        }
        #pragma unroll
        for (int t = 0; t < 4; t++)
            #pragma unroll
            for (int r = 0; r < 4; r++)
                sA[ROT(mi * 16 + quad * 4 + r, (nb + t) * 16 + ln)] = acc[t][r];
    }
    __syncthreads();

    // ---- Phase9: f2 = elu(a2 + max bsrc2[idx]) ; pool partials -> sB[0..511]
    {
        const int mi = wv >> 1, nb = (wv & 1) * 4;
        unsigned plo[4], phi[4];
        #pragma unroll
        for (int r = 0; r < 4; r++) {
            const int rr = mi * 16 + quad * 4 + r;
            plo[r] = sCu[2 * rr];
            phi[r] = sCu[2 * rr + 1];
        }
        float ps[4] = {0.f, 0.f, 0.f, 0.f};
        #pragma unroll
        for (int t = 0; t < 4; t++) {
            const int cc = (nb + t) * 16 + ln;
            #pragma unroll
            for (int r = 0; r < 4; r++) {
                float mx = -INF_F;
                #pragma unroll
                for (int j = 0; j < 8; j++) {
                    const int s = (int)(((j < 4) ? (plo[r] >> (8 * j))
                                                 : (phi[r] >> (8 * (j - 4)))) & 63u);
                    mx = fmaxf(mx, sA[ROT(s, cc)]);
                }
                ps[t] += elu_fast(a2acc[t][r] + mx);
            }
        }
        #pragma unroll
        for (int t = 0; t < 4; t++) {
            ps[t] += __shfl_xor(ps[t], 16, 64);
            ps[t] += __shfl_xor(ps[t], 32, 64);
        }
        if (lane < 16)
            #pragma unroll
            for (int t = 0; t < 4; t++)
                sB[mi * 128 + (nb + t) * 16 + lane] = ps[t];
    }
    __syncthreads();

    // ---- Head
    if (tid < 128) {
        const float p = (sB[tid] + sB[128 + tid] + sB[256 + tid] + sB[384 + tid]) * (1.f / 64.f);
        sB[512 + tid] = p;
    }
    __syncthreads();
    if (tid < 64) {
        float acc = b_o1[tid];
        for (int d = 0; d < 128; d++) acc = fmaf(sB[512 + d], W_o1[d * 64 + tid], acc);
        sB[640 + tid] = elu_fast(acc);
    }
    __syncthreads();
    if (tid < 32) {
        float acc = b_o2[tid];
        for (int d = 0; d < 64; d++) acc = fmaf(sB[640 + d], W_o2[d * 32 + tid], acc);
        sB[704 + tid] = elu_fast(acc);
    }
    __syncthreads();
    if (tid < 4) {
        float acc = b_o3[tid];
        for (int d = 0; d < 32; d++) acc = fmaf(sB[704 + d], W_o3[d * 4 + tid], acc);
        sB[736 + tid] = elu_fast(acc);
    }
    __syncthreads();
    if (tid == 0) {
        float acc = b_o4[0];
        #pragma unroll
        for (int d = 0; d < 4; d++) acc = fmaf(sB[736 + d], W_o4[d], acc);
        out[g] = acc;
        out[G_ + g] = (float)g;
    }
}

// ================= vector fallback (round-4 kernel, inline weight diffs) =================
__global__ __launch_bounds__(TPB, 4)
void fused_vec(const float* __restrict__ x_sv,  const float* __restrict__ x_trk,
               const float* __restrict__ W_sv1, const float* __restrict__ b_sv1,
               const float* __restrict__ W_sv2, const float* __restrict__ b_sv2,
               const float* __restrict__ W_trk1,const float* __restrict__ b_trk1,
               const float* __restrict__ W_trk2,const float* __restrict__ b_trk2,
               const float* __restrict__ W_c1,  const float* __restrict__ b_c1,
               const float* __restrict__ W_c2,  const float* __restrict__ b_c2,
               const float* __restrict__ W_o1,  const float* __restrict__ b_o1,
               const float* __restrict__ W_o2,  const float* __restrict__ b_o2,
               const float* __restrict__ W_o3,  const float* __restrict__ b_o3,
               const float* __restrict__ W_o4,  const float* __restrict__ b_o4,
               float* __restrict__ out)
{
    __shared__ float sA[8192];
    __shared__ float sB[8192];
    __shared__ float sC[4096];
    const int g    = blockIdx.x;
    const int tid  = threadIdx.x;
    const int c128 = tid & 127;
    const int g4   = tid >> 7;
    const int cq   = tid & 31;
    const int c0   = cq * 4;
    const int rg   = tid >> 5;
    const int lane_hi = tid & 32;

    sC[2048 + tid] = x_trk[(size_t)g * 512 + tid];
    if (tid < 32) sC[2560 + tid] = x_sv[(size_t)g * 32 + tid];
    __syncthreads();
    {
        float w[8];
        #pragma unroll
        for (int k = 0; k < 8; k++) w[k] = W_trk1[k * 128 + c128];
        const float b1 = b_trk1[c128];
        #pragma unroll
        for (int i = 0; i < 16; i++) {
            const int r = g4 * 16 + i;
            float acc = b1;
            #pragma unroll
            for (int k = 0; k < 8; k++) acc = fmaf(sC[2048 + r * 8 + k], w[k], acc);
            sB[r * 128 + c128] = elu_ref(acc);
        }
    }
    __syncthreads();
    {
        const int r0 = rg * 4;
        float4 acc[4];
        const float4 bz = *(const float4*)&b_trk2[c0];
        #pragma unroll
        for (int i = 0; i < 4; i++) acc[i] = bz;
        for (int d0 = 0; d0 < 128; d0 += 4) {
            const float4 w0 = *(const float4*)&W_trk2[(d0 + 0) * 128 + c0];
            const float4 w1 = *(const float4*)&W_trk2[(d0 + 1) * 128 + c0];
            const float4 w2 = *(const float4*)&W_trk2[(d0 + 2) * 128 + c0];
            const float4 w3 = *(const float4*)&W_trk2[(d0 + 3) * 128 + c0];
            #pragma unroll
            for (int i = 0; i < 4; i++) {
                const float4 h = *(const float4*)&sB[(r0 + i) * 128 + d0];
                FMA4(acc[i], h.x, w0); FMA4(acc[i], h.y, w1);
                FMA4(acc[i], h.z, w2); FMA4(acc[i], h.w, w3);
            }
        }
        #pragma unroll
        for (int i = 0; i < 4; i++) {
            float4 r;
            r.x = fmaxf(acc[i].x, 0.f); r.y = fmaxf(acc[i].y, 0.f);
            r.z = fmaxf(acc[i].z, 0.f); r.w = fmaxf(acc[i].w, 0.f);
            *(float4*)&sA[ROT(r0 + i, c0)] = r;
        }
    }
    __syncthreads();
    {
        const float w0 = W_sv1[c128], w1 = W_sv1[128 + c128];
        const float b1 = b_sv1[c128];
        #pragma unroll
        for (int i = 0; i < 4; i++) {
            const int s = g4 * 4 + i;
            sB[s * 128 + c128] =
                elu_ref(fmaf(sC[2560 + s * 2 + 1], w1, fmaf(sC[2560 + s * 2], w0, b1)));
        }
    }
    __syncthreads();
    {
        const int s = rg;
        float4 acc = *(const float4*)&b_sv2[c0];
        for (int d0 = 0; d0 < 128; d0 += 4) {
            const float4 w0 = *(const float4*)&W_sv2[(d0 + 0) * 128 + c0];
            const float4 w1 = *(const float4*)&W_sv2[(d0 + 1) * 128 + c0];
            const float4 w2 = *(const float4*)&W_sv2[(d0 + 2) * 128 + c0];
            const float4 w3 = *(const float4*)&W_sv2[(d0 + 3) * 128 + c0];
            const float4 h = *(const float4*)&sB[s * 128 + d0];
            FMA4(acc, h.x, w0); FMA4(acc, h.y, w1);
            FMA4(acc, h.z, w2); FMA4(acc, h.w, w3);
        }
        float4 r;
        r.x = fmaxf(acc.x, 0.f); r.y = fmaxf(acc.y, 0.f);
        r.z = fmaxf(acc.z, 0.f); r.w = fmaxf(acc.w, 0.f);
        *(float4*)&sC[ROT(s, c0)] = r;
    }
    __syncthreads();
    unsigned pack1;
    {
        {
            const int s = rg;
            float4 acc = {0.f, 0.f, 0.f, 0.f};
            for (int d0 = 0; d0 < 128; d0 += 4) {
                const float4 e  = *(const float4*)&sC[ROT(s, d0)];
                const float4 w0 = *(const float4*)&W_c1[(128 + d0 + 0) * 128 + c0];
                const float4 w1 = *(const float4*)&W_c1[(128 + d0 + 1) * 128 + c0];
                const float4 w2 = *(const float4*)&W_c1[(128 + d0 + 2) * 128 + c0];
                const float4 w3 = *(const float4*)&W_c1[(128 + d0 + 3) * 128 + c0];
                FMA4(acc, e.x, w0); FMA4(acc, e.y, w1);
                FMA4(acc, e.z, w2); FMA4(acc, e.w, w3);
            }
            *(float4*)&sC[BS1(s, c0)] = acc;
        }
        const int q  = tid >> 3;
        const int s0 = tid & 7;
        float d0a = 0.f, d1a = 0.f, n0 = 0.f, n1 = 0.f;
        for (int d0 = 0; d0 < 128; d0 += 4) {
            const float4 t  = *(const float4*)&sA[ROT(q, d0)];
            const float4 v0 = *(const float4*)&sC[ROT(s0, d0)];
            const float4 v1 = *(const float4*)&sC[ROT(s0 + 8, d0)];
            d0a += t.x * v0.x + t.y * v0.y + t.z * v0.z + t.w * v0.w;
            d1a += t.x * v1.x + t.y * v1.y + t.z * v1.z + t.w * v1.w;
            n0  += v0.x * v0.x + v0.y * v0.y + v0.z * v0.z + v0.w * v0.w;
            n1  += v1.x * v1.x + v1.y * v1.y + v1.z * v1.z + v1.w * v1.w;
        }
        float sc0 = fmaf(-2.f, d0a, n0);
        float sc1 = fmaf(-2.f, d1a, n1);
        pack1 = 0u;
        #pragma unroll
        for (int r = 0; r < 8; r++) {
            float bv = sc0; int bs = s0;
            if (sc1 < bv) { bv = sc1; bs = s0 + 8; }
            #pragma unroll
            for (int o = 1; o <= 4; o <<= 1) {
                const float ov = __shfl_xor(bv, o, 8);
                const int   os = __shfl_xor(bs, o, 8);
                if (ov < bv || (ov == bv && os < bs)) { bv = ov; bs = os; }
            }
            pack1 |= (unsigned)bs << (4 * r);
            if (bs == s0)     sc0 = INF_F;
            if (bs == s0 + 8) sc1 = INF_F;
        }
    }
    __syncthreads();
    float4 a2v[4];
    {
        const int q0 = rg * 4;
        float4 a1[4];
        const float4 bc1 = *(const float4*)&b_c1[c0];
        const float4 bc2 = *(const float4*)&b_c2[c0];
        #pragma unroll
        for (int i = 0; i < 4; i++) { a1[i] = bc1; a2v[i] = bc2; }
        for (int d0 = 0; d0 < 128; d0 += 4) {
            float4 t[4];
            #pragma unroll
            for (int i = 0; i < 4; i++) t[i] = *(const float4*)&sA[ROT(q0 + i, d0)];
            #pragma unroll
            for (int dj = 0; dj < 4; dj++) {
                float4 wv;
                const float4 wa = *(const float4*)&W_c1[(d0 + dj) * 128 + c0];
                const float4 wb = *(const float4*)&W_c1[(128 + d0 + dj) * 128 + c0];
                wv.x = wa.x - wb.x; wv.y = wa.y - wb.y;
                wv.z = wa.z - wb.z; wv.w = wa.w - wb.w;
                FMA4(a1[0], ((const float*)&t[0])[dj], wv);
                FMA4(a1[1], ((const float*)&t[1])[dj], wv);
                FMA4(a1[2], ((const float*)&t[2])[dj], wv);
                FMA4(a1[3], ((const float*)&t[3])[dj], wv);
            }
            #pragma unroll
            for (int dj = 0; dj < 4; dj++) {
                float4 wv;
                const float4 wa = *(const float4*)&W_c2[(d0 + dj) * 128 + c0];
                const float4 wb = *(const float4*)&W_c2[(128 + d0 + dj) * 128 + c0];
                wv.x = wa.x - wb.x; wv.y = wa.y - wb.y;
                wv.z = wa.z - wb.z; wv.w = wa.w - wb.w;
                FMA4(a2v[0], ((const float*)&t[0])[dj], wv);
                FMA4(a2v[1], ((const float*)&t[1])[dj], wv);
                FMA4(a2v[2], ((const float*)&t[2])[dj], wv);
                FMA4(a2v[3], ((const float*)&t[3])[dj], wv);
            }
        }
        #pragma unroll
        for (int i = 0; i < 4; i++) {
            const int q = q0 + i;
            const unsigned pk = __shfl(pack1, 8 * i + lane_hi);
            float4 m = {-INF_F, -INF_F, -INF_F, -INF_F};
            #pragma unroll
            for (int j = 0; j < 8; j++) {
                const int s = (int)((pk >> (4 * j)) & 15u);
                const float4 b = *(const float4*)&sC[BS1(s, c0)];
                MAX4(m, b);
            }
            float4 f;
            f.x = elu_ref(a1[i].x + m.x); f.y = elu_ref(a1[i].y + m.y);
            f.z = elu_ref(a1[i].z + m.z); f.w = elu_ref(a1[i].w + m.w);
            *(float4*)&sB[ROT(q, c0)] = f;
        }
    }
    __syncthreads();
    {
        const int s  = tid & 63;
        const int q0 = (tid >> 6) * 8;
        float acc[8];
        #pragma unroll
        for (int i = 0; i < 8; i++) acc[i] = 0.f;
        float nrm = 0.f;
        for (int d0 = 0; d0 < 128; d0 += 4) {
            const float4 f = *(const float4*)&sB[ROT(s, d0)];
            nrm = fmaf(f.x, f.x, nrm); nrm = fmaf(f.y, f.y, nrm);
            nrm = fmaf(f.z, f.z, nrm); nrm = fmaf(f.w, f.w, nrm);
            #pragma unroll
            for (int i = 0; i < 8; i++) {
                const float4 t = *(const float4*)&sA[ROT(q0 + i, d0)];
                acc[i] = fmaf(t.x, f.x, acc[i]); acc[i] = fmaf(t.y, f.y, acc[i]);
                acc[i] = fmaf(t.z, f.z, acc[i]); acc[i] = fmaf(t.w, f.w, acc[i]);
            }
        }
        #pragma unroll
        for (int i = 0; i < 8; i++)
            sC[(q0 + i) * 64 + s] = fmaf(-2.f, acc[i], nrm);
    }
    __syncthreads();
    unsigned lo2, hi2;
    {
        const int q = tid >> 3;
        const int j = tid & 7;
        float v[8];
        *(float4*)&v[0] = *(const float4*)&sC[q * 64 + 8 * j];
        *(float4*)&v[4] = *(const float4*)&sC[q * 64 + 8 * j + 4];
        lo2 = 0u; hi2 = 0u;
        #pragma unroll
        for (int r = 0; r < 8; r++) {
            float bv = v[0]; int bs = 8 * j;
            #pragma unroll
            for (int t = 1; t < 8; t++)
                if (v[t] < bv) { bv = v[t]; bs = 8 * j + t; }
            #pragma unroll
            for (int o = 1; o <= 4; o <<= 1) {
                const float ov = __shfl_xor(bv, o, 8);
                const int   os = __shfl_xor(bs, o, 8);
                if (ov < bv || (ov == bv && os < bs)) { bv = ov; bs = os; }
            }
            if (r < 4) lo2 |= (unsigned)bs << (8 * r);
            else       hi2 |= (unsigned)bs << (8 * (r - 4));
            #pragma unroll
            for (int t = 0; t < 8; t++)
                if (bs == 8 * j + t) v[t] = INF_F;
        }
        const int r0 = rg * 4;
        float4 acc[4];
        #pragma unroll
        for (int i = 0; i < 4; i++) acc[i] = make_float4(0.f, 0.f, 0.f, 0.f);
        for (int d0 = 0; d0 < 128; d0 += 4) {
            const float4 w0 = *(const float4*)&W_c2[(128 + d0 + 0) * 128 + c0];
            const float4 w1 = *(const float4*)&W_c2[(128 + d0 + 1) * 128 + c0];
            const float4 w2 = *(const float4*)&W_c2[(128 + d0 + 2) * 128 + c0];
            const float4 w3 = *(const float4*)&W_c2[(128 + d0 + 3) * 128 + c0];
            #pragma unroll
            for (int i = 0; i < 4; i++) {
                const float4 f = *(const float4*)&sB[ROT(r0 + i, d0)];
                FMA4(acc[i], f.x, w0); FMA4(acc[i], f.y, w1);
                FMA4(acc[i], f.z, w2); FMA4(acc[i], f.w, w3);
            }
        }
        #pragma unroll
        for (int i = 0; i < 4; i++)
            *(float4*)&sA[ROT(r0 + i, c0)] = acc[i];
    }
    __syncthreads();
    {
        const int q0 = rg * 4;
        float4 ps = {0.f, 0.f, 0.f, 0.f};
        #pragma unroll
        for (int i = 0; i < 4; i++) {
            const unsigned plo = __shfl(lo2, 8 * i + lane_hi);
            const unsigned phi = __shfl(hi2, 8 * i + lane_hi);
            float4 m = {-INF_F, -INF_F, -INF_F, -INF_F};
            #pragma unroll
            for (int j = 0; j < 8; j++) {
                const int s = (int)(((j < 4) ? (plo >> (8 * j)) : (phi >> (8 * (j - 4)))) & 63u);
                const float4 b = *(const float4*)&sA[ROT(s, c0)];
                MAX4(m, b);
            }
            ps.x += elu_ref(a2v[i].x + m.x); ps.y += elu_ref(a2v[i].y + m.y);
            ps.z += elu_ref(a2v[i].z + m.z); ps.w += elu_ref(a2v[i].w + m.w);
        }
        *(float4*)&sB[rg * 128 + c0] = ps;
    }
    __syncthreads();
    if (tid < 128) {
        float p = 0.f;
        #pragma unroll
        for (int t = 0; t < 16; t++) p += sB[t * 128 + tid];
        sB[2048 + tid] = p * (1.f / 64.f);
    }
    __syncthreads();
    if (tid < 64) {
        float acc = b_o1[tid];
        for (int d = 0; d < 128; d++) acc = fmaf(sB[2048 + d], W_o1[d * 64 + tid], acc);
        sB[2176 + tid] = elu_ref(acc);
    }
    __syncthreads();
    if (tid < 32) {
        float acc = b_o2[tid];
        for (int d = 0; d < 64; d++) acc = fmaf(sB[2176 + d], W_o2[d * 32 + tid], acc);
        sB[2240 + tid] = elu_ref(acc);
    }
    __syncthreads();
    if (tid < 4) {
        float acc = b_o3[tid];
        for (int d = 0; d < 32; d++) acc = fmaf(sB[2240 + d], W_o3[d * 4 + tid], acc);
        sB[2272 + tid] = elu_ref(acc);
    }
    __syncthreads();
    if (tid == 0) {
        float acc = b_o4[0];
        #pragma unroll
        for (int d = 0; d < 4; d++) acc = fmaf(sB[2272 + d], W_o4[d], acc);
        out[g] = acc;
        out[G_ + g] = (float)g;
    }
}

extern "C" void kernel_launch(void* const* d_in, const int* in_sizes, int n_in,
                              void* d_out, int out_size, void* d_ws, size_t ws_size,
                              hipStream_t stream) {
    const float* x_sv   = (const float*)d_in[0];
    const float* x_trk  = (const float*)d_in[1];
    const float* W_sv1  = (const float*)d_in[2];
    const float* b_sv1  = (const float*)d_in[3];
    const float* W_sv2  = (const float*)d_in[4];
    const float* b_sv2  = (const float*)d_in[5];
    const float* W_trk1 = (const float*)d_in[6];
    const float* b_trk1 = (const float*)d_in[7];
    const float* W_trk2 = (const float*)d_in[8];
    const float* b_trk2 = (const float*)d_in[9];
    const float* W_c1   = (const float*)d_in[10];
    const float* b_c1   = (const float*)d_in[11];
    const float* W_c2   = (const float*)d_in[12];
    const float* b_c2   = (const float*)d_in[13];
    const float* W_o1   = (const float*)d_in[14];
    const float* b_o1   = (const float*)d_in[15];
    const float* W_o2   = (const float*)d_in[16];
    const float* b_o2   = (const float*)d_in[17];
    const float* W_o3   = (const float*)d_in[18];
    const float* b_o3   = (const float*)d_in[19];
    const float* W_o4   = (const float*)d_in[20];
    const float* b_o4   = (const float*)d_in[21];
    float* out = (float*)d_out;

    const size_t WS_NEED = (size_t)6 * 3 * 16384 * sizeof(unsigned short); // 576 KB
    if (ws_size >= WS_NEED && d_ws != nullptr) {
        unsigned short* wsu = (unsigned short*)d_ws;
        prep_pack<<<384, 256, 0, stream>>>(W_trk2, W_sv2, W_c1, W_c2, wsu);
        fused_mfma<<<G_, TPB, 0, stream>>>(x_sv, x_trk, W_sv1, b_sv1, b_sv2,
                                           W_trk1, b_trk1, b_trk2, b_c1, b_c2,
                                           W_o1, b_o1, W_o2, b_o2, W_o3, b_o3,
                                           W_o4, b_o4, wsu, out);
    } else {
        fused_vec<<<G_, TPB, 0, stream>>>(x_sv, x_trk, W_sv1, b_sv1, W_sv2, b_sv2,
                                          W_trk1, b_trk1, W_trk2, b_trk2,
                                          W_c1, b_c1, W_c2, b_c2,
                                          W_o1, b_o1, W_o2, b_o2, W_o3, b_o3,
                                          W_o4, b_o4, out);
    }
}